// Round 1
// baseline (45073.608 us; speedup 1.0000x reference)
//
#include <hip/hip_runtime.h>
#include <math.h>

#define BB 8
#define LL 512
#define DD 256
#define NG4 1024
#define GR 8     // reader WGs per batch
#define RU 32    // reader units per WG
#define GW 32    // writer WGs per batch
#define WR 16    // writer mem rows per WG
#define WU 8     // writer units per WG
#define MLD 264  // padded leading dim for mems tile

// ---- workspace layout (float offsets) ----
static const size_t SZ_XW    = (size_t)BB*LL*NG4;              // 4,194,304
static const size_t SZ_OC    = (size_t)BB*LL*DD;               // 1,048,576
static const size_t OFF_XW   = 0;
static const size_t OFF_P    = OFF_XW + SZ_XW;
static const size_t OFF_OC   = OFF_P + SZ_XW;
static const size_t OFF_BM   = OFF_OC + SZ_OC;
static const size_t OFF_OSEQ = OFF_BM + (size_t)DD*NG4;
static const size_t OFF_H    = OFF_OSEQ + SZ_OC;
static const size_t OFF_PMAX = OFF_H + (size_t)BB*2*DD;
static const size_t OFF_PSUM = OFF_PMAX + (size_t)BB*32;
static const size_t OFF_PM   = OFF_PSUM + (size_t)BB*32;
static const size_t OFF_BARS = OFF_PM + (size_t)BB*32*DD;
static const size_t TOTAL_WS = OFF_BARS + 16*64;               // floats

__device__ __forceinline__ float hsig(float x) {
    return fminf(fmaxf(0.2f*x + 0.5f, 0.0f), 1.0f);
}

// monotonically-increasing-counter barrier among one batch's WGs
__device__ __forceinline__ void batch_barrier(unsigned* ctr, unsigned target) {
    __threadfence();              // release my stores (agent scope)
    __syncthreads();              // whole WG done + fenced
    if (threadIdx.x == 0) {
        __hip_atomic_fetch_add(ctr, 1u, __ATOMIC_RELEASE, __HIP_MEMORY_SCOPE_AGENT);
        while (__hip_atomic_load(ctr, __ATOMIC_RELAXED, __HIP_MEMORY_SCOPE_AGENT) < target) { }
    }
    __syncthreads();
    __threadfence();              // acquire for all threads
}

// ---- simple fp32 tiled GEMM: C[m][n] = bias[n] + sum_k A[m][k]*B[k][n] ----
template<int TM, int TN, int TK>
__global__ void __launch_bounds__(256) gemm_nn(
    const float* __restrict__ A, int lda,
    const float* __restrict__ Bmat, int ldb,
    const float* __restrict__ bias,
    float* __restrict__ C, int ldc,
    int M, int N, int K)
{
    __shared__ float As[TK][TM];
    __shared__ float Bs[TK][TN];
    const int m0 = blockIdx.y * TM, n0 = blockIdx.x * TN;
    const int tid = threadIdx.x;
    const int tx = tid % (TN/4);
    const int ty = tid / (TN/4);
    float acc[4][4] = {};
    for (int k0 = 0; k0 < K; k0 += TK) {
        {
            const int e = tid*4;
            const int m = e / TK, k = e % TK;
            const float4 v = *reinterpret_cast<const float4*>(&A[(size_t)(m0+m)*lda + k0 + k]);
            As[k+0][m] = v.x; As[k+1][m] = v.y; As[k+2][m] = v.z; As[k+3][m] = v.w;
        }
        {
            const int e = tid*4;
            const int k = e / TN, n = e % TN;
            const float4 v = *reinterpret_cast<const float4*>(&Bmat[(size_t)(k0+k)*ldb + n0 + n]);
            Bs[k][n+0] = v.x; Bs[k][n+1] = v.y; Bs[k][n+2] = v.z; Bs[k][n+3] = v.w;
        }
        __syncthreads();
        #pragma unroll
        for (int kk = 0; kk < TK; ++kk) {
            float a[4], bv[4];
            #pragma unroll
            for (int i = 0; i < 4; ++i) a[i] = As[kk][ty*4+i];
            #pragma unroll
            for (int j = 0; j < 4; ++j) bv[j] = Bs[kk][tx*4+j];
            #pragma unroll
            for (int i = 0; i < 4; ++i)
                #pragma unroll
                for (int j = 0; j < 4; ++j) acc[i][j] += a[i]*bv[j];
        }
        __syncthreads();
    }
    #pragma unroll
    for (int i = 0; i < 4; ++i) {
        const int m = m0 + ty*4 + i;
        #pragma unroll
        for (int j = 0; j < 4; ++j) {
            const int n = n0 + tx*4 + j;
            C[(size_t)m*ldc + n] = acc[i][j] + (bias ? bias[n] : 0.0f);
        }
    }
}

// ---- reader LSTM: persistent, 8 WGs per batch, U_r slice in LDS ----
__global__ void __launch_bounds__(256) reader_kernel(
    const float* __restrict__ XW, const float* __restrict__ Ur,
    float* __restrict__ oseq, unsigned* __restrict__ bars)
{
    extern __shared__ float sm[];
    float* Us  = sm;                 // [256][128]: col cl = g*32+u  -> U_r[:, g*256+U0+u]
    float* hs  = Us + 256*128;       // 256
    float* red = hs + 256;           // 256
    float* zb  = red + 256;          // 128
    float* cst = zb + 128;           // 32

    const int b  = (int)blockIdx.x & (BB-1);   // batch -> XCD-friendly
    const int wg = (int)blockIdx.x / BB;       // 0..7
    const int U0 = wg * RU;
    const int tid = threadIdx.x;

    {   // load U_r slice, coalesced-ish
        const int u = tid & 31, p = tid >> 5;
        for (int it = 0; it < 128; ++it) {
            const int pair = it*8 + p;         // 0..1023
            const int k = pair >> 2, g = pair & 3;
            Us[k*128 + g*32 + u] = Ur[(size_t)k*NG4 + g*DD + U0 + u];
        }
    }
    if (tid < RU) cst[tid] = 0.0f;
    __syncthreads();

    unsigned* bar = bars + b*64;
    unsigned epoch = 0;

    for (int t = 0; t < LL; ++t) {
        float xw_pref = 0.0f;
        if (tid < 128) {
            xw_pref = XW[((size_t)b*LL + t)*NG4 + (size_t)(tid>>5)*DD + U0 + (tid&31)];
        }
        hs[tid] = (t == 0) ? 0.0f : oseq[((size_t)b*LL + (t-1))*DD + tid];
        __syncthreads();

        {   // z partial: 128 cols x 2 k-halves
            const int cl = tid & 127;
            const int kbase = (tid >> 7) * 128;
            const float* us = Us + cl;
            float a0 = 0.f, a1 = 0.f, a2 = 0.f, a3 = 0.f;
            #pragma unroll 8
            for (int k = 0; k < 128; k += 4) {
                a0 += us[(size_t)(kbase+k+0)*128] * hs[kbase+k+0];
                a1 += us[(size_t)(kbase+k+1)*128] * hs[kbase+k+1];
                a2 += us[(size_t)(kbase+k+2)*128] * hs[kbase+k+2];
                a3 += us[(size_t)(kbase+k+3)*128] * hs[kbase+k+3];
            }
            red[tid] = (a0+a1)+(a2+a3);
        }
        __syncthreads();
        if (tid < 128) zb[tid] = red[tid] + red[tid+128] + xw_pref;
        __syncthreads();
        if (tid < RU) {
            const float ig = hsig(zb[tid]);
            const float fg = hsig(zb[32+tid]);
            const float gg = tanhf(zb[64+tid]);
            const float og = hsig(zb[96+tid]);
            const float c  = fg*cst[tid] + ig*gg;
            cst[tid] = c;
            oseq[((size_t)b*LL + t)*DD + U0 + tid] = og * tanhf(c);
        }
        ++epoch;
        batch_barrier(bar, epoch*GR);
    }
}

// ---- writer loop: persistent, 32 WGs per batch; mem rows + weight slices in LDS ----
__global__ void __launch_bounds__(256) writer_kernel(
    const float* __restrict__ x, const float* __restrict__ oseq,
    const float* __restrict__ P, const float* __restrict__ Uw,
    const float* __restrict__ Bm, float* __restrict__ hstate,
    float* __restrict__ pmax, float* __restrict__ psum, float* __restrict__ pm,
    float* __restrict__ out, unsigned* __restrict__ bars)
{
    extern __shared__ float sm[];
    float* mems = sm;                   // [16][MLD]
    float* Uws  = mems + WR*MLD;        // [256][32] col cl=g*8+u -> U_w[:, g*256+U0+u]
    float* Bms  = Uws + 256*32;         // [256][32]
    float* hs   = Bms + 256*32;         // 256
    float* os   = hs + 256;             // 256
    float* ms   = os + 256;             // 256
    float* red  = ms + 256;             // 256
    float* ssx  = red + 256;            // 16
    float* esx  = ssx + 16;             // 16
    float* fw   = esx + 16;             // 32
    float* zl   = fw + 32;              // 32
    float* cw   = zl + 32;              // 8
    float* misc = cw + 8;               // [0]=scale prev, [1]=mw, [2]=gmax, [3]=S

    const int b  = (int)blockIdx.x & (BB-1);
    const int wg = (int)blockIdx.x / BB;   // 0..31
    const int R0 = wg * WR;
    const int U0 = wg * WU;
    const int tid = threadIdx.x;
    const int r16 = tid >> 4, s16 = tid & 15;

    for (int it = 0; it < 32; ++it) {
        const int cl = tid & 31, kk = tid >> 5;
        const int k = it*8 + kk;
        const int g = cl >> 3, u = cl & 7;
        Uws[k*32 + cl] = Uw[(size_t)k*NG4 + g*DD + U0 + u];
        Bms[k*32 + cl] = Bm[(size_t)k*NG4 + g*DD + U0 + u];
    }
    for (int idx = tid; idx < WR*DD; idx += 256) {
        const int r = idx >> 8, d = idx & 255;
        mems[r*MLD + d] = x[((size_t)b*LL + R0 + r)*DD + d];
    }
    if (tid < WU) cw[tid] = 0.0f;
    __syncthreads();

    unsigned* bar = bars + (BB + b)*64;
    unsigned epoch = 0;

    for (int t = 0; t < LL; ++t) {
        float p_pref = 0.0f;
        if (tid < 32) {
            p_pref = P[((size_t)b*LL + t)*NG4 + (size_t)(tid>>3)*DD + U0 + (tid&7)];
        }
        hs[tid] = (t == 0) ? 0.0f : hstate[(size_t)b*2*DD + (size_t)(t&1)*DD + tid];
        os[tid] = oseq[((size_t)b*LL + t)*DD + tid];
        __syncthreads();

        // phase A: apply deferred mem update from step t-1
        if (t > 0) {
            const float scale = misc[0];
            for (int idx = tid; idx < WR*DD; idx += 256) {
                const int r = idx >> 8, d = idx & 255;
                const float z = esx[r] * scale;
                float* mp = &mems[r*MLD + d];
                *mp = *mp * (1.0f - z) + hs[d] * z;
            }
        }
        __syncthreads();

        // scores for owned rows
        {
            float a = 0.f;
            const float* mrow = mems + r16*MLD;
            for (int d = s16; d < DD; d += 16) a += os[d]*mrow[d];
            #pragma unroll
            for (int off = 8; off; off >>= 1) a += __shfl_down(a, off, 16);
            if (s16 == 0) ssx[r16] = a;
        }
        __syncthreads();
        if (tid == 0) {
            float mw = ssx[0];
            #pragma unroll
            for (int r = 1; r < WR; ++r) mw = fmaxf(mw, ssx[r]);
            misc[1] = mw;
            pmax[b*32 + wg] = mw;
        }
        __syncthreads();
        const float mw = misc[1];
        if (tid < WR) esx[tid] = expf(ssx[tid] - mw);
        __syncthreads();
        if (tid == 0) {
            float s = 0.f;
            #pragma unroll
            for (int r = 0; r < WR; ++r) s += esx[r];
            psum[b*32 + wg] = s;
        }
        {   // weighted-mem partial
            float s = 0.f;
            #pragma unroll
            for (int r = 0; r < WR; ++r) s += esx[r]*mems[r*MLD + tid];
            pm[((size_t)b*32 + wg)*DD + tid] = s;
        }
        ++epoch;
        batch_barrier(bar, epoch*GW);

        // phase B: combine partial softmax
        {
            float v = (tid < 32) ? pmax[b*32 + tid] : -1e30f;
            #pragma unroll
            for (int off = 16; off; off >>= 1) v = fmaxf(v, __shfl_xor(v, off, 32));
            if (tid == 0) misc[2] = v;
        }
        __syncthreads();
        const float gmax = misc[2];
        if (tid < 32) fw[tid] = expf(pmax[b*32 + tid] - gmax);
        __syncthreads();
        if (tid == 0) {
            float S = 0.f;
            #pragma unroll
            for (int w = 0; w < 32; ++w) S += psum[b*32 + w]*fw[w];
            misc[3] = S;
            misc[0] = fw[wg] / S;   // scale for next step's deferred mem update
        }
        {
            float s = 0.f;
            #pragma unroll
            for (int w = 0; w < 32; ++w) s += pm[((size_t)b*32 + w)*DD + tid]*fw[w];
            red[tid] = s;
        }
        __syncthreads();
        const float S = misc[3];
        ms[tid] = red[tid] / S;      // m_rt
        __syncthreads();

        // z_w GEMV: 32 cols x 8 k-chunks
        {
            const int cl = tid & 31;
            const int k0 = (tid >> 5) * 32;
            float a = 0.f;
            #pragma unroll 8
            for (int k = k0; k < k0+32; ++k)
                a += hs[k]*Uws[k*32 + cl] + ms[k]*Bms[k*32 + cl];
            red[tid] = a;
        }
        __syncthreads();
        if (tid < 32) {
            float z = 0.f;
            #pragma unroll
            for (int s = 0; s < 8; ++s) z += red[tid + s*32];
            zl[tid] = z + p_pref;
        }
        __syncthreads();
        if (tid < WU) {
            const float ig = hsig(zl[tid]);
            const float fg = hsig(zl[8+tid]);
            const float gg = tanhf(zl[16+tid]);
            const float og = hsig(zl[24+tid]);
            const float c  = fg*cw[tid] + ig*gg;
            cw[tid] = c;
            const float h = og * tanhf(c);
            hstate[(size_t)b*2*DD + (size_t)((t+1)&1)*DD + U0 + tid] = h;
            if (t == LL-1) out[b*DD + U0 + tid] = h;
        }
        ++epoch;
        batch_barrier(bar, epoch*GW);
    }
}

extern "C" void kernel_launch(void* const* d_in, const int* in_sizes, int n_in,
                              void* d_out, int out_size, void* d_ws, size_t ws_size,
                              hipStream_t stream) {
    const float* x   = (const float*)d_in[0];
    const float* W_r = (const float*)d_in[1];
    const float* U_r = (const float*)d_in[2];
    const float* b_r = (const float*)d_in[3];
    const float* W_w = (const float*)d_in[4];
    const float* U_w = (const float*)d_in[5];
    const float* b_w = (const float*)d_in[6];
    const float* W_c = (const float*)d_in[7];
    const float* b_c = (const float*)d_in[8];
    (void)in_sizes; (void)n_in;

    if (ws_size < TOTAL_WS * sizeof(float)) return;   // clean failure instead of corruption

    float* ws    = (float*)d_ws;
    float* XW    = ws + OFF_XW;
    float* P     = ws + OFF_P;
    float* OC    = ws + OFF_OC;
    float* Bmw   = ws + OFF_BM;
    float* oseq  = ws + OFF_OSEQ;
    float* hst   = ws + OFF_H;
    float* pmax  = ws + OFF_PMAX;
    float* psum  = ws + OFF_PSUM;
    float* pm    = ws + OFF_PM;
    unsigned* bars = (unsigned*)(ws + OFF_BARS);

    const int READER_LDS = (256*128 + 256 + 256 + 128 + 32) * 4;
    const int WRITER_LDS = (WR*MLD + 256*32*2 + 256*4 + 16+16+32+32+8+8) * 4;
    hipFuncSetAttribute((const void*)reader_kernel, hipFuncAttributeMaxDynamicSharedMemorySize, READER_LDS);
    hipFuncSetAttribute((const void*)writer_kernel, hipFuncAttributeMaxDynamicSharedMemorySize, WRITER_LDS);

    hipMemsetAsync(bars, 0, 16*64*sizeof(unsigned), stream);

    dim3 blk(256);
    // XW = x @ W_r + b_r        (4096 x 1024, K=256)
    gemm_nn<64,64,16><<<dim3(NG4/64, (BB*LL)/64), blk, 0, stream>>>(
        x, DD, W_r, NG4, b_r, XW, NG4, BB*LL, NG4, DD);
    // Bm = W_c[256:,:] @ W_w    (256 x 1024, K=256)
    gemm_nn<64,64,16><<<dim3(NG4/64, DD/64), blk, 0, stream>>>(
        W_c + (size_t)DD*DD, DD, W_w, NG4, nullptr, Bmw, NG4, DD, NG4, DD);
    // reader (writes oseq)
    reader_kernel<<<BB*GR, blk, READER_LDS, stream>>>(XW, U_r, oseq, bars);
    // OC = oseq @ W_c[:256,:] + b_c    (4096 x 256, K=256)
    gemm_nn<64,64,16><<<dim3(DD/64, (BB*LL)/64), blk, 0, stream>>>(
        oseq, DD, W_c, DD, b_c, OC, DD, BB*LL, DD, DD);
    // P = OC @ W_w + b_w        (4096 x 1024, K=256)
    gemm_nn<64,64,16><<<dim3(NG4/64, (BB*LL)/64), blk, 0, stream>>>(
        OC, DD, W_w, NG4, b_w, P, NG4, BB*LL, NG4, DD);
    // writer (writes d_out)
    writer_kernel<<<BB*GW, blk, WRITER_LDS, stream>>>(
        x, oseq, P, U_w, Bmw, hst, pmax, psum, pm, (float*)d_out, bars);
}

// Round 2
// 7494.106 us; speedup vs baseline: 6.0145x; 6.0145x over previous
//
#include <hip/hip_runtime.h>
#include <math.h>

#define BB 8
#define LL 512
#define DD 256
#define NG4 1024
#define GR 8     // reader WGs per batch
#define RU 32    // reader units per WG
#define GW 32    // writer WGs per batch
#define WR 16    // writer mem rows per WG
#define WU 8     // writer units per WG
#define MLD 264  // padded leading dim for mems tile

// ---- workspace layout (float offsets) ----
static const size_t SZ_XW    = (size_t)BB*LL*NG4;              // 4,194,304
static const size_t SZ_OC    = (size_t)BB*LL*DD;               // 1,048,576
static const size_t OFF_XW   = 0;
static const size_t OFF_P    = OFF_XW + SZ_XW;
static const size_t OFF_OC   = OFF_P + SZ_XW;
static const size_t OFF_BM   = OFF_OC + SZ_OC;
static const size_t OFF_OSEQ = OFF_BM + (size_t)DD*NG4;
static const size_t OFF_H    = OFF_OSEQ + SZ_OC;
static const size_t OFF_PMAX = OFF_H + (size_t)BB*2*DD;
static const size_t OFF_PSUM = OFF_PMAX + (size_t)BB*32;
static const size_t OFF_PM   = OFF_PSUM + (size_t)BB*32;
static const size_t OFF_BARS = OFF_PM + (size_t)BB*32*DD;
static const size_t TOTAL_WS = OFF_BARS + 16*64;               // floats

__device__ __forceinline__ float hsig(float x) {
    return fminf(fmaxf(0.2f*x + 0.5f, 0.0f), 1.0f);
}

// coherent (MALL-level, sc1) scalar access — bypasses the incoherent per-XCD L2s
__device__ __forceinline__ void st_coh(float* p, float v) {
    __hip_atomic_store(p, v, __ATOMIC_RELAXED, __HIP_MEMORY_SCOPE_AGENT);
}
__device__ __forceinline__ float ld_coh(const float* p) {
    return __hip_atomic_load(p, __ATOMIC_RELAXED, __HIP_MEMORY_SCOPE_AGENT);
}

// fence-free barrier: callers must have issued ALL cross-WG data via st_coh.
// Per-wave vmcnt(0) retires those stores at the coherence point; then count.
__device__ __forceinline__ void fast_barrier(unsigned* ctr, unsigned target) {
    asm volatile("s_waitcnt vmcnt(0)" ::: "memory");
    __syncthreads();
    if (threadIdx.x == 0) {
        __hip_atomic_fetch_add(ctr, 1u, __ATOMIC_RELAXED, __HIP_MEMORY_SCOPE_AGENT);
        while (__hip_atomic_load(ctr, __ATOMIC_RELAXED, __HIP_MEMORY_SCOPE_AGENT) < target) { }
    }
    __syncthreads();
}

// ---- simple fp32 tiled GEMM: C[m][n] = bias[n] + sum_k A[m][k]*B[k][n] ----
template<int TM, int TN, int TK>
__global__ void __launch_bounds__(256) gemm_nn(
    const float* __restrict__ A, int lda,
    const float* __restrict__ Bmat, int ldb,
    const float* __restrict__ bias,
    float* __restrict__ C, int ldc,
    int M, int N, int K)
{
    __shared__ float As[TK][TM];
    __shared__ float Bs[TK][TN];
    const int m0 = blockIdx.y * TM, n0 = blockIdx.x * TN;
    const int tid = threadIdx.x;
    const int tx = tid % (TN/4);
    const int ty = tid / (TN/4);
    float acc[4][4] = {};
    for (int k0 = 0; k0 < K; k0 += TK) {
        {
            const int e = tid*4;
            const int m = e / TK, k = e % TK;
            const float4 v = *reinterpret_cast<const float4*>(&A[(size_t)(m0+m)*lda + k0 + k]);
            As[k+0][m] = v.x; As[k+1][m] = v.y; As[k+2][m] = v.z; As[k+3][m] = v.w;
        }
        {
            const int e = tid*4;
            const int k = e / TN, n = e % TN;
            const float4 v = *reinterpret_cast<const float4*>(&Bmat[(size_t)(k0+k)*ldb + n0 + n]);
            Bs[k][n+0] = v.x; Bs[k][n+1] = v.y; Bs[k][n+2] = v.z; Bs[k][n+3] = v.w;
        }
        __syncthreads();
        #pragma unroll
        for (int kk = 0; kk < TK; ++kk) {
            float a[4], bv[4];
            #pragma unroll
            for (int i = 0; i < 4; ++i) a[i] = As[kk][ty*4+i];
            #pragma unroll
            for (int j = 0; j < 4; ++j) bv[j] = Bs[kk][tx*4+j];
            #pragma unroll
            for (int i = 0; i < 4; ++i)
                #pragma unroll
                for (int j = 0; j < 4; ++j) acc[i][j] += a[i]*bv[j];
        }
        __syncthreads();
    }
    #pragma unroll
    for (int i = 0; i < 4; ++i) {
        const int m = m0 + ty*4 + i;
        #pragma unroll
        for (int j = 0; j < 4; ++j) {
            const int n = n0 + tx*4 + j;
            C[(size_t)m*ldc + n] = acc[i][j] + (bias ? bias[n] : 0.0f);
        }
    }
}

// ---- reader LSTM: persistent, 8 WGs per batch, U_r slice in LDS ----
__global__ void __launch_bounds__(256) reader_kernel(
    const float* __restrict__ XW, const float* __restrict__ Ur,
    float* __restrict__ oseq, unsigned* __restrict__ bars)
{
    extern __shared__ float sm[];
    float* Us  = sm;                 // [256][128]: col cl = g*32+u  -> U_r[:, g*256+U0+u]
    float* hs  = Us + 256*128;       // 256
    float* red = hs + 256;           // 256
    float* zb  = red + 256;          // 128
    float* cst = zb + 128;           // 32

    const int b  = (int)blockIdx.x & (BB-1);   // batch -> XCD-friendly
    const int wg = (int)blockIdx.x / BB;       // 0..7
    const int U0 = wg * RU;
    const int tid = threadIdx.x;

    {   // load U_r slice
        const int u = tid & 31, p = tid >> 5;
        for (int it = 0; it < 128; ++it) {
            const int pair = it*8 + p;         // 0..1023
            const int k = pair >> 2, g = pair & 3;
            Us[k*128 + g*32 + u] = Ur[(size_t)k*NG4 + g*DD + U0 + u];
        }
    }
    if (tid < RU) cst[tid] = 0.0f;
    __syncthreads();

    unsigned* bar = bars + b*64;
    unsigned epoch = 0;

    for (int t = 0; t < LL; ++t) {
        float xw_pref = 0.0f;
        if (tid < 128) {
            xw_pref = XW[((size_t)b*LL + t)*NG4 + (size_t)(tid>>5)*DD + U0 + (tid&31)];
        }
        hs[tid] = (t == 0) ? 0.0f : ld_coh(&oseq[((size_t)b*LL + (t-1))*DD + tid]);
        __syncthreads();

        {   // z partial: 128 cols x 2 k-halves
            const int cl = tid & 127;
            const int kbase = (tid >> 7) * 128;
            const float* us = Us + cl;
            float a0 = 0.f, a1 = 0.f, a2 = 0.f, a3 = 0.f;
            #pragma unroll 8
            for (int k = 0; k < 128; k += 4) {
                a0 += us[(size_t)(kbase+k+0)*128] * hs[kbase+k+0];
                a1 += us[(size_t)(kbase+k+1)*128] * hs[kbase+k+1];
                a2 += us[(size_t)(kbase+k+2)*128] * hs[kbase+k+2];
                a3 += us[(size_t)(kbase+k+3)*128] * hs[kbase+k+3];
            }
            red[tid] = (a0+a1)+(a2+a3);
        }
        __syncthreads();
        if (tid < 128) zb[tid] = red[tid] + red[tid+128] + xw_pref;
        __syncthreads();
        if (tid < RU) {
            const float ig = hsig(zb[tid]);
            const float fg = hsig(zb[32+tid]);
            const float gg = tanhf(zb[64+tid]);
            const float og = hsig(zb[96+tid]);
            const float c  = fg*cst[tid] + ig*gg;
            cst[tid] = c;
            st_coh(&oseq[((size_t)b*LL + t)*DD + U0 + tid], og * tanhf(c));
        }
        ++epoch;
        fast_barrier(bar, epoch*GR);
    }
}

// ---- writer loop: persistent, 32 WGs per batch; mem rows + weight slices in LDS ----
__global__ void __launch_bounds__(256) writer_kernel(
    const float* __restrict__ x, const float* __restrict__ oseq,
    const float* __restrict__ P, const float* __restrict__ Uw,
    const float* __restrict__ Bm, float* __restrict__ hstate,
    float* __restrict__ pmax, float* __restrict__ psum, float* __restrict__ pm,
    float* __restrict__ out, unsigned* __restrict__ bars)
{
    extern __shared__ float sm[];
    float* mems = sm;                   // [16][MLD]
    float* Uws  = mems + WR*MLD;        // [256][32] col cl=g*8+u -> U_w[:, g*256+U0+u]
    float* Bms  = Uws + 256*32;         // [256][32]
    float* hs   = Bms + 256*32;         // 256
    float* os   = hs + 256;             // 256
    float* ms   = os + 256;             // 256
    float* red  = ms + 256;             // 256
    float* ssx  = red + 256;            // 16
    float* esx  = ssx + 16;             // 16
    float* fwS  = esx + 16;             // 32
    float* zl   = fwS + 32;             // 32
    float* cw   = zl + 32;              // 8
    float* misc = cw + 8;               // [0]=scale prev, [1]=mw, [3]=S

    const int b  = (int)blockIdx.x & (BB-1);
    const int wg = (int)blockIdx.x / BB;   // 0..31
    const int R0 = wg * WR;
    const int U0 = wg * WU;
    const int tid = threadIdx.x;
    const int r16 = tid >> 4, s16 = tid & 15;

    for (int it = 0; it < 32; ++it) {
        const int cl = tid & 31, kk = tid >> 5;
        const int k = it*8 + kk;
        const int g = cl >> 3, u = cl & 7;
        Uws[k*32 + cl] = Uw[(size_t)k*NG4 + g*DD + U0 + u];
        Bms[k*32 + cl] = Bm[(size_t)k*NG4 + g*DD + U0 + u];
    }
    for (int idx = tid; idx < WR*DD; idx += 256) {
        const int r = idx >> 8, d = idx & 255;
        mems[r*MLD + d] = x[((size_t)b*LL + R0 + r)*DD + d];
    }
    if (tid < WU) cw[tid] = 0.0f;
    __syncthreads();

    unsigned* bar = bars + (BB + b)*64;
    unsigned epoch = 0;

    for (int t = 0; t < LL; ++t) {
        float p_pref = 0.0f;
        if (tid < 32) {
            p_pref = P[((size_t)b*LL + t)*NG4 + (size_t)(tid>>3)*DD + U0 + (tid&7)];
        }
        hs[tid] = (t == 0) ? 0.0f : ld_coh(&hstate[(size_t)b*2*DD + (size_t)(t&1)*DD + tid]);
        os[tid] = oseq[((size_t)b*LL + t)*DD + tid];
        __syncthreads();

        // phase A: apply deferred mem update from step t-1
        if (t > 0) {
            const float scale = misc[0];
            for (int idx = tid; idx < WR*DD; idx += 256) {
                const int r = idx >> 8, d = idx & 255;
                const float z = esx[r] * scale;
                float* mp = &mems[r*MLD + d];
                *mp = *mp * (1.0f - z) + hs[d] * z;
            }
        }
        __syncthreads();

        // scores for owned rows
        {
            float a = 0.f;
            const float* mrow = mems + r16*MLD;
            for (int d = s16; d < DD; d += 16) a += os[d]*mrow[d];
            #pragma unroll
            for (int off = 8; off; off >>= 1) a += __shfl_down(a, off, 16);
            if (s16 == 0) ssx[r16] = a;
        }
        __syncthreads();
        if (tid == 0) {
            float mw = ssx[0];
            #pragma unroll
            for (int r = 1; r < WR; ++r) mw = fmaxf(mw, ssx[r]);
            misc[1] = mw;
            st_coh(&pmax[b*32 + wg], mw);
        }
        __syncthreads();
        const float mw = misc[1];
        if (tid < WR) esx[tid] = __expf(ssx[tid] - mw);
        __syncthreads();
        if (tid == 0) {
            float s = 0.f;
            #pragma unroll
            for (int r = 0; r < WR; ++r) s += esx[r];
            st_coh(&psum[b*32 + wg], s);
        }
        {   // weighted-mem partial
            float s = 0.f;
            #pragma unroll
            for (int r = 0; r < WR; ++r) s += esx[r]*mems[r*MLD + tid];
            st_coh(&pm[((size_t)b*32 + wg)*DD + tid], s);
        }
        ++epoch;
        fast_barrier(bar, epoch*GW);

        // phase B: combine partial softmax (32-lane shuffle reduction)
        if (tid < 32) {
            const float v = ld_coh(&pmax[b*32 + tid]);
            float g = v;
            #pragma unroll
            for (int off = 16; off; off >>= 1) g = fmaxf(g, __shfl_xor(g, off, 32));
            const float fw_t = __expf(v - g);
            float sv = ld_coh(&psum[b*32 + tid]) * fw_t;
            #pragma unroll
            for (int off = 16; off; off >>= 1) sv += __shfl_xor(sv, off, 32);
            fwS[tid] = fw_t;
            if (tid == 0) misc[3] = sv;
            if (tid == wg) misc[0] = fw_t / sv;   // scale for next step's deferred mem update
        }
        __syncthreads();
        {
            float s = 0.f;
            #pragma unroll
            for (int w = 0; w < 32; ++w)
                s += ld_coh(&pm[((size_t)b*32 + w)*DD + tid]) * fwS[w];
            ms[tid] = s / misc[3];      // m_rt
        }
        __syncthreads();

        // z_w GEMV: 32 cols x 8 k-chunks
        {
            const int cl = tid & 31;
            const int k0 = (tid >> 5) * 32;
            float a = 0.f;
            #pragma unroll 8
            for (int k = k0; k < k0+32; ++k)
                a += hs[k]*Uws[k*32 + cl] + ms[k]*Bms[k*32 + cl];
            red[tid] = a;
        }
        __syncthreads();
        if (tid < 32) {
            float z = 0.f;
            #pragma unroll
            for (int s = 0; s < 8; ++s) z += red[tid + s*32];
            zl[tid] = z + p_pref;
        }
        __syncthreads();
        if (tid < WU) {
            const float ig = hsig(zl[tid]);
            const float fg = hsig(zl[8+tid]);
            const float gg = tanhf(zl[16+tid]);
            const float og = hsig(zl[24+tid]);
            const float c  = fg*cw[tid] + ig*gg;
            cw[tid] = c;
            const float h = og * tanhf(c);
            st_coh(&hstate[(size_t)b*2*DD + (size_t)((t+1)&1)*DD + U0 + tid], h);
            if (t == LL-1) out[b*DD + U0 + tid] = h;
        }
        ++epoch;
        fast_barrier(bar, epoch*GW);
    }
}

extern "C" void kernel_launch(void* const* d_in, const int* in_sizes, int n_in,
                              void* d_out, int out_size, void* d_ws, size_t ws_size,
                              hipStream_t stream) {
    const float* x   = (const float*)d_in[0];
    const float* W_r = (const float*)d_in[1];
    const float* U_r = (const float*)d_in[2];
    const float* b_r = (const float*)d_in[3];
    const float* W_w = (const float*)d_in[4];
    const float* U_w = (const float*)d_in[5];
    const float* b_w = (const float*)d_in[6];
    const float* W_c = (const float*)d_in[7];
    const float* b_c = (const float*)d_in[8];
    (void)in_sizes; (void)n_in;

    if (ws_size < TOTAL_WS * sizeof(float)) return;

    float* ws    = (float*)d_ws;
    float* XW    = ws + OFF_XW;
    float* P     = ws + OFF_P;
    float* OC    = ws + OFF_OC;
    float* Bmw   = ws + OFF_BM;
    float* oseq  = ws + OFF_OSEQ;
    float* hst   = ws + OFF_H;
    float* pmax  = ws + OFF_PMAX;
    float* psum  = ws + OFF_PSUM;
    float* pm    = ws + OFF_PM;
    unsigned* bars = (unsigned*)(ws + OFF_BARS);

    const int READER_LDS = (256*128 + 256 + 256 + 128 + 32) * 4;
    const int WRITER_LDS = (WR*MLD + 256*32*2 + 256*4 + 16+16+32+32+8+8) * 4;
    hipFuncSetAttribute((const void*)reader_kernel, hipFuncAttributeMaxDynamicSharedMemorySize, READER_LDS);
    hipFuncSetAttribute((const void*)writer_kernel, hipFuncAttributeMaxDynamicSharedMemorySize, WRITER_LDS);

    hipMemsetAsync(bars, 0, 16*64*sizeof(unsigned), stream);

    dim3 blk(256);
    // XW = x @ W_r + b_r        (4096 x 1024, K=256)
    gemm_nn<64,64,16><<<dim3(NG4/64, (BB*LL)/64), blk, 0, stream>>>(
        x, DD, W_r, NG4, b_r, XW, NG4, BB*LL, NG4, DD);
    // Bm = W_c[256:,:] @ W_w    (256 x 1024, K=256)
    gemm_nn<64,64,16><<<dim3(NG4/64, DD/64), blk, 0, stream>>>(
        W_c + (size_t)DD*DD, DD, W_w, NG4, nullptr, Bmw, NG4, DD, NG4, DD);
    // reader (writes oseq)
    reader_kernel<<<BB*GR, blk, READER_LDS, stream>>>(XW, U_r, oseq, bars);
    // OC = oseq @ W_c[:256,:] + b_c    (4096 x 256, K=256)
    gemm_nn<64,64,16><<<dim3(DD/64, (BB*LL)/64), blk, 0, stream>>>(
        oseq, DD, W_c, DD, b_c, OC, DD, BB*LL, DD, DD);
    // P = OC @ W_w + b_w        (4096 x 1024, K=256)
    gemm_nn<64,64,16><<<dim3(NG4/64, (BB*LL)/64), blk, 0, stream>>>(
        OC, DD, W_w, NG4, b_w, P, NG4, BB*LL, NG4, DD);
    // writer (writes d_out)
    writer_kernel<<<BB*GW, blk, WRITER_LDS, stream>>>(
        x, oseq, P, U_w, Bmw, hst, pmax, psum, pm, (float*)d_out, bars);
}

// Round 3
// 4711.142 us; speedup vs baseline: 9.5674x; 1.5907x over previous
//
#include <hip/hip_runtime.h>
#include <math.h>

#define BB 8
#define LL 512
#define DD 256
#define NG4 1024
#define WGB 32     // WGs per batch
#define WR 16      // mem rows per WG
#define WU 8       // units per WG
#define MLD 264    // padded leading dim for mems tile

typedef __attribute__((ext_vector_type(4))) float f32x4;

// ---- workspace layout (float offsets) ----
static const size_t OFF_XW    = 0;
static const size_t OFF_F     = OFF_XW + (size_t)BB*LL*NG4;     // F = Wc_top @ Ww   (256x1024)
static const size_t OFF_BMW   = OFF_F + (size_t)DD*NG4;         // Bm = Wc_bot @ Ww  (256x1024)
static const size_t OFF_B2    = OFF_BMW + (size_t)DD*NG4;       // b2 = b_c@Ww + b_w (1024)
static const size_t OFF_HR    = OFF_B2 + NG4;                   // [2][B][256] h_r double buffer
static const size_t OFF_HW    = OFF_HR + (size_t)2*BB*DD;       // [B][256]   h_w
static const size_t OFF_PMAX  = OFF_HW + (size_t)BB*DD;         // [B][32]
static const size_t OFF_PSUM  = OFF_PMAX + (size_t)BB*WGB;      // [B][32]
static const size_t OFF_PM    = OFF_PSUM + (size_t)BB*WGB;      // [B][32][256]
static const size_t OFF_FLAGS = OFF_PM + (size_t)BB*WGB*DD;     // [B][32] u32 epochs
static const size_t TOTAL_WS  = OFF_FLAGS + BB*WGB;             // floats

__device__ __forceinline__ float hsig(float x) {
    return fminf(fmaxf(0.2f*x + 0.5f, 0.0f), 1.0f);
}

// coherent (bypass per-XCD L2) scalar access
__device__ __forceinline__ void st_coh(float* p, float v) {
    __hip_atomic_store(p, v, __ATOMIC_RELAXED, __HIP_MEMORY_SCOPE_AGENT);
}
__device__ __forceinline__ float ld_coh(const float* p) {
    return __hip_atomic_load(p, __ATOMIC_RELAXED, __HIP_MEMORY_SCOPE_AGENT);
}
__device__ __forceinline__ void st_coh_u(unsigned* p, unsigned v) {
    __hip_atomic_store(p, v, __ATOMIC_RELAXED, __HIP_MEMORY_SCOPE_AGENT);
}
__device__ __forceinline__ unsigned ld_coh_u(const unsigned* p) {
    return __hip_atomic_load(p, __ATOMIC_RELAXED, __HIP_MEMORY_SCOPE_AGENT);
}

// 8 coherent float4 loads, single drain at the end (pipelined at MALL)
__device__ __forceinline__ void ld_pm8(
    const f32x4* p0, const f32x4* p1, const f32x4* p2, const f32x4* p3,
    const f32x4* p4, const f32x4* p5, const f32x4* p6, const f32x4* p7,
    f32x4& a0, f32x4& a1, f32x4& a2, f32x4& a3,
    f32x4& a4, f32x4& a5, f32x4& a6, f32x4& a7)
{
    asm volatile(
        "global_load_dwordx4 %0, %8, off sc0 sc1\n\t"
        "global_load_dwordx4 %1, %9, off sc0 sc1\n\t"
        "global_load_dwordx4 %2, %10, off sc0 sc1\n\t"
        "global_load_dwordx4 %3, %11, off sc0 sc1\n\t"
        "global_load_dwordx4 %4, %12, off sc0 sc1\n\t"
        "global_load_dwordx4 %5, %13, off sc0 sc1\n\t"
        "global_load_dwordx4 %6, %14, off sc0 sc1\n\t"
        "global_load_dwordx4 %7, %15, off sc0 sc1\n\t"
        "s_waitcnt vmcnt(0)"
        : "=&v"(a0), "=&v"(a1), "=&v"(a2), "=&v"(a3),
          "=&v"(a4), "=&v"(a5), "=&v"(a6), "=&v"(a7)
        : "v"(p0), "v"(p1), "v"(p2), "v"(p3),
          "v"(p4), "v"(p5), "v"(p6), "v"(p7)
        : "memory");
}

// flag-array barrier: each WG publishes a monotonically increasing epoch to
// its own dword; wave 0 polls all 32 flags with one coherent load per lane.
__device__ __forceinline__ void flag_barrier(unsigned* flb, int wg, unsigned target, int tid) {
    asm volatile("s_waitcnt vmcnt(0)" ::: "memory");  // drain this thread's coherent stores
    __syncthreads();                                  // whole WG drained
    if (tid == 0) st_coh_u(&flb[wg], target);
    if (tid < 64) {
        unsigned v;
        do {
            v = ld_coh_u(&flb[tid & 31]);
        } while (!__all(v >= target));
    }
    __syncthreads();
}

// ---- simple fp32 tiled GEMM: C[m][n] = bias[n] + sum_k A[m][k]*B[k][n] ----
template<int TM, int TN, int TK>
__global__ void __launch_bounds__(256) gemm_nn(
    const float* __restrict__ A, int lda,
    const float* __restrict__ Bmat, int ldb,
    const float* __restrict__ bias,
    float* __restrict__ C, int ldc,
    int M, int N, int K)
{
    __shared__ float As[TK][TM];
    __shared__ float Bs[TK][TN];
    const int m0 = blockIdx.y * TM, n0 = blockIdx.x * TN;
    const int tid = threadIdx.x;
    const int tx = tid % (TN/4);
    const int ty = tid / (TN/4);
    float acc[4][4] = {};
    for (int k0 = 0; k0 < K; k0 += TK) {
        {
            const int e = tid*4;
            const int m = e / TK, k = e % TK;
            const float4 v = *reinterpret_cast<const float4*>(&A[(size_t)(m0+m)*lda + k0 + k]);
            As[k+0][m] = v.x; As[k+1][m] = v.y; As[k+2][m] = v.z; As[k+3][m] = v.w;
        }
        {
            const int e = tid*4;
            const int k = e / TN, n = e % TN;
            const float4 v = *reinterpret_cast<const float4*>(&Bmat[(size_t)(k0+k)*ldb + n0 + n]);
            Bs[k][n+0] = v.x; Bs[k][n+1] = v.y; Bs[k][n+2] = v.z; Bs[k][n+3] = v.w;
        }
        __syncthreads();
        #pragma unroll
        for (int kk = 0; kk < TK; ++kk) {
            float a[4], bv[4];
            #pragma unroll
            for (int i = 0; i < 4; ++i) a[i] = As[kk][ty*4+i];
            #pragma unroll
            for (int j = 0; j < 4; ++j) bv[j] = Bs[kk][tx*4+j];
            #pragma unroll
            for (int i = 0; i < 4; ++i)
                #pragma unroll
                for (int j = 0; j < 4; ++j) acc[i][j] += a[i]*bv[j];
        }
        __syncthreads();
    }
    #pragma unroll
    for (int i = 0; i < 4; ++i) {
        const int m = m0 + ty*4 + i;
        #pragma unroll
        for (int j = 0; j < 4; ++j) {
            const int n = n0 + tx*4 + j;
            C[(size_t)m*ldc + n] = acc[i][j] + (bias ? bias[n] : 0.0f);
        }
    }
}

// b2[n] = b_w[n] + sum_k b_c[k]*W_w[k][n]
__global__ void __launch_bounds__(256) b2_kernel(
    const float* __restrict__ bc, const float* __restrict__ Ww,
    const float* __restrict__ bw, float* __restrict__ B2)
{
    const int n = blockIdx.x*256 + threadIdx.x;
    float a = bw[n];
    for (int k = 0; k < DD; ++k) a += bc[k]*Ww[(size_t)k*NG4 + n];
    B2[n] = a;
}

// ---- fused reader+writer persistent kernel: 32 WGs per batch ----
// merged step s = 0..512: reader computes h_r[s] (s<512); writer handles
// tau = s-1 (s>=1). 2 flag-barriers per step.
__global__ void __launch_bounds__(256) fused_kernel(
    const float* __restrict__ XW, const float* __restrict__ Fw,
    const float* __restrict__ Bm, const float* __restrict__ B2,
    const float* __restrict__ Ur, const float* __restrict__ Uw,
    const float* __restrict__ x,
    float* __restrict__ HR, float* __restrict__ HWb,
    float* __restrict__ PMAX, float* __restrict__ PSUM, float* __restrict__ PM,
    unsigned* __restrict__ flags, float* __restrict__ out)
{
    extern __shared__ float sm[];
    float* Urs  = sm;              // [256][32]
    float* Uws  = Urs + 8192;      // [256][32]
    float* Fs   = Uws + 8192;      // [256][32]
    float* Bms  = Fs + 8192;       // [256][32]
    float* mems = Bms + 8192;      // [16][MLD]
    float* hr   = mems + WR*MLD;   // 256 : h_r[s-1] (= o_tau)
    float* hw   = hr + 256;        // 256 : h_w[s-2]
    float* ms   = hw + 256;        // 256 : m_rt
    float* zredR= ms + 256;        // 256
    float* zredW= zredR + 256;     // 256
    float* red4 = zredW + 256;     // [4][256]
    float* xws  = red4 + 1024;     // 32
    float* zrs  = xws + 32;        // 32
    float* g1s  = zrs + 32;        // 32
    float* zws  = g1s + 32;        // 32
    float* b2s  = zws + 32;        // 32
    float* fwS  = b2s + 32;        // 32
    float* ssx  = fwS + 32;        // 16
    float* esx  = ssx + 16;        // 16
    float* cr   = esx + 16;        // 8
    float* cw   = cr + 8;          // 8
    float* misc = cw + 8;          // [0]=scale(prev z), [1]=invS

    const int b   = (int)blockIdx.x & 7;    // team -> same XCD (heuristic)
    const int wg  = (int)blockIdx.x >> 3;   // 0..31
    const int tid = threadIdx.x;
    const int R0  = wg*WR;
    const int U0  = wg*WU;

    // --- init: weight slices (col cl -> global col (cl>>3)*256 + U0 + (cl&7)) ---
    for (int it = 0; it < 32; ++it) {
        const int e = it*256 + tid;
        const int k = e >> 5, cl = e & 31;
        const int gc = (cl>>3)*DD + U0 + (cl&7);
        Urs[k*32+cl] = Ur[(size_t)k*NG4 + gc];
        Uws[k*32+cl] = Uw[(size_t)k*NG4 + gc];
        Fs [k*32+cl] = Fw[(size_t)k*NG4 + gc];
        Bms[k*32+cl] = Bm[(size_t)k*NG4 + gc];
    }
    if (tid < 32) b2s[tid] = B2[(tid>>3)*DD + U0 + (tid&7)];
    for (int r = 0; r < WR; ++r)
        mems[r*MLD + tid] = x[((size_t)b*LL + R0 + r)*DD + tid];
    if (tid < 8) { cr[tid] = 0.f; cw[tid] = 0.f; }
    __syncthreads();

    unsigned* flb = flags + b*WGB;

    for (int s = 0; s <= LL; ++s) {
        const bool doR = (s < LL), doW = (s >= 1);

        // ---- A1: loads ----
        if (doR && tid < 32)
            xws[tid] = XW[((size_t)b*LL + s)*NG4 + (tid>>3)*DD + U0 + (tid&7)];
        hr[tid] = (s >= 1) ? ld_coh(&HR[((size_t)((s-1)&1))*BB*DD + b*DD + tid]) : 0.f;
        hw[tid] = (s >= 2) ? ld_coh(&HWb[b*DD + tid]) : 0.f;
        __syncthreads();

        // ---- A2: deferred mem update (z from tau-1 = s-2, h_w[s-2]) ----
        if (s >= 2) {
            const float scale = misc[0];
            const float hwd = hw[tid];
            #pragma unroll
            for (int r = 0; r < WR; ++r) {
                const float z = esx[r]*scale;
                float* mp = &mems[r*MLD + tid];
                *mp = *mp*(1.f - z) + hwd*z;
            }
        }
        __syncthreads();

        // ---- A3: scores (o_tau = hr) + GEMV partials ----
        if (doW) {
            const int r = tid >> 4, j = tid & 15;
            float a = 0.f;
            const float* mrow = mems + r*MLD;
            #pragma unroll 4
            for (int d = j; d < DD; d += 16) a += hr[d]*mrow[d];
            #pragma unroll
            for (int off = 8; off; off >>= 1) a += __shfl_down(a, off, 16);
            if (j == 0) ssx[r] = a;
        }
        {
            const int kc = tid >> 5, cl = tid & 31;
            const int k0 = kc*32;
            float aR = 0.f, aW = 0.f;
            #pragma unroll 8
            for (int k = k0; k < k0+32; ++k) {
                aR += hr[k]*Urs[k*32+cl];
                aW += hw[k]*Uws[k*32+cl] + hr[k]*Fs[k*32+cl];
            }
            zredR[tid] = aR; zredW[tid] = aW;
        }
        __syncthreads();

        // ---- A4: local softmax | zr reduce | g1 reduce (parallel waves) ----
        if (tid < 16) {
            const float v = ssx[tid];
            float m = v;
            #pragma unroll
            for (int off = 8; off; off >>= 1) m = fmaxf(m, __shfl_xor(m, off, 16));
            const float e = __expf(v - m);
            esx[tid] = e;
            float sum = e;
            #pragma unroll
            for (int off = 8; off; off >>= 1) sum += __shfl_xor(sum, off, 16);
            if (tid == 0 && doW) {
                st_coh(&PMAX[b*WGB + wg], m);
                st_coh(&PSUM[b*WGB + wg], sum);
            }
        } else if (tid >= 64 && tid < 96) {
            const int cl = tid - 64;
            float z = xws[cl];
            #pragma unroll
            for (int q = 0; q < 8; ++q) z += zredR[q*32 + cl];
            zrs[cl] = z;
        } else if (tid >= 128 && tid < 160) {
            const int cl = tid - 128;
            float z = b2s[cl];
            #pragma unroll
            for (int q = 0; q < 8; ++q) z += zredW[q*32 + cl];
            g1s[cl] = z;
        }
        __syncthreads();

        // ---- A5: pm partial + reader gates ----
        if (doW) {
            float p = 0.f;
            #pragma unroll
            for (int r = 0; r < WR; ++r) p += esx[r]*mems[r*MLD + tid];
            st_coh(&PM[((size_t)b*WGB + wg)*DD + tid], p);
        }
        if (doR && tid < 8) {
            const float ig = hsig(zrs[tid]);
            const float fg = hsig(zrs[8+tid]);
            const float gg = tanhf(zrs[16+tid]);
            const float og = hsig(zrs[24+tid]);
            const float c  = fg*cr[tid] + ig*gg;
            cr[tid] = c;
            st_coh(&HR[((size_t)(s&1))*BB*DD + b*DD + U0 + tid], og*tanhf(c));
        }
        flag_barrier(flb, wg, 2u*(unsigned)s + 1u, tid);

        // ---- phase B (writer tau = s-1) ----
        if (doW) {
            // B1: global softmax weights
            if (tid < 32) {
                const float pmx = ld_coh(&PMAX[b*WGB + tid]);
                const float ps  = ld_coh(&PSUM[b*WGB + tid]);
                float g = pmx;
                #pragma unroll
                for (int off = 16; off; off >>= 1) g = fmaxf(g, __shfl_xor(g, off, 32));
                const float fw = __expf(pmx - g);
                float S = ps*fw;
                #pragma unroll
                for (int off = 16; off; off >>= 1) S += __shfl_xor(S, off, 32);
                fwS[tid] = fw;
                if (tid == 0)  misc[1] = 1.f/S;
                if (tid == wg) misc[0] = fw/S;   // scale for next step's mem update
            }
            __syncthreads();
            // B2: combine pm partials (8 coherent float4 loads)
            {
                const int w0 = tid >> 6, dq = tid & 63;
                const float* pmb = PM + (size_t)b*WGB*DD;
                const f32x4* p0 = (const f32x4*)(pmb + (w0+ 0)*DD) + dq;
                const f32x4* p1 = (const f32x4*)(pmb + (w0+ 4)*DD) + dq;
                const f32x4* p2 = (const f32x4*)(pmb + (w0+ 8)*DD) + dq;
                const f32x4* p3 = (const f32x4*)(pmb + (w0+12)*DD) + dq;
                const f32x4* p4 = (const f32x4*)(pmb + (w0+16)*DD) + dq;
                const f32x4* p5 = (const f32x4*)(pmb + (w0+20)*DD) + dq;
                const f32x4* p6 = (const f32x4*)(pmb + (w0+24)*DD) + dq;
                const f32x4* p7 = (const f32x4*)(pmb + (w0+28)*DD) + dq;
                f32x4 a0,a1,a2,a3,a4,a5,a6,a7;
                ld_pm8(p0,p1,p2,p3,p4,p5,p6,p7, a0,a1,a2,a3,a4,a5,a6,a7);
                f32x4 acc = a0*fwS[w0];
                acc += a1*fwS[w0+4];  acc += a2*fwS[w0+8];
                acc += a3*fwS[w0+12]; acc += a4*fwS[w0+16];
                acc += a5*fwS[w0+20]; acc += a6*fwS[w0+24];
                acc += a7*fwS[w0+28];
                *(f32x4*)(red4 + w0*DD + dq*4) = acc;
            }
            __syncthreads();
            // B3: m_rt
            ms[tid] = (red4[tid] + red4[DD+tid] + red4[2*DD+tid] + red4[3*DD+tid]) * misc[1];
            __syncthreads();
            // B4: GEMV ms@Bms
            {
                const int kc = tid >> 5, cl = tid & 31, k0 = kc*32;
                float a = 0.f;
                #pragma unroll 8
                for (int k = k0; k < k0+32; ++k) a += ms[k]*Bms[k*32+cl];
                zredW[tid] = a;
            }
            __syncthreads();
            if (tid < 32) {
                float z = g1s[tid];
                #pragma unroll
                for (int q = 0; q < 8; ++q) z += zredW[q*32 + tid];
                zws[tid] = z;
            }
            __syncthreads();
            if (tid < 8) {
                const float ig = hsig(zws[tid]);
                const float fg = hsig(zws[8+tid]);
                const float gg = tanhf(zws[16+tid]);
                const float og = hsig(zws[24+tid]);
                const float c  = fg*cw[tid] + ig*gg;
                cw[tid] = c;
                const float h = og*tanhf(c);
                st_coh(&HWb[b*DD + U0 + tid], h);
                if (s == LL) out[b*DD + U0 + tid] = h;
            }
        }
        if (s < LL) flag_barrier(flb, wg, 2u*(unsigned)s + 2u, tid);
    }
}

extern "C" void kernel_launch(void* const* d_in, const int* in_sizes, int n_in,
                              void* d_out, int out_size, void* d_ws, size_t ws_size,
                              hipStream_t stream) {
    const float* x   = (const float*)d_in[0];
    const float* W_r = (const float*)d_in[1];
    const float* U_r = (const float*)d_in[2];
    const float* b_r = (const float*)d_in[3];
    const float* W_w = (const float*)d_in[4];
    const float* U_w = (const float*)d_in[5];
    const float* b_w = (const float*)d_in[6];
    const float* W_c = (const float*)d_in[7];
    const float* b_c = (const float*)d_in[8];
    (void)in_sizes; (void)n_in;

    if (ws_size < TOTAL_WS * sizeof(float)) return;

    float* ws   = (float*)d_ws;
    float* XW   = ws + OFF_XW;
    float* Fmat = ws + OFF_F;
    float* Bmw  = ws + OFF_BMW;
    float* B2   = ws + OFF_B2;
    float* HR   = ws + OFF_HR;
    float* HWb  = ws + OFF_HW;
    float* PMAX = ws + OFF_PMAX;
    float* PSUM = ws + OFF_PSUM;
    float* PM   = ws + OFF_PM;
    unsigned* flags = (unsigned*)(ws + OFF_FLAGS);

    const int FUSED_LDS = 39540 * 4;   // 158160 B
    hipFuncSetAttribute((const void*)fused_kernel, hipFuncAttributeMaxDynamicSharedMemorySize, FUSED_LDS);

    hipMemsetAsync(flags, 0, BB*WGB*sizeof(unsigned), stream);

    dim3 blk(256);
    // XW = x @ W_r + b_r        (4096 x 1024, K=256)
    gemm_nn<64,64,16><<<dim3(NG4/64, (BB*LL)/64), blk, 0, stream>>>(
        x, DD, W_r, NG4, b_r, XW, NG4, BB*LL, NG4, DD);
    // F  = W_c[:256,:] @ W_w    (256 x 1024, K=256)
    gemm_nn<64,64,16><<<dim3(NG4/64, DD/64), blk, 0, stream>>>(
        W_c, DD, W_w, NG4, nullptr, Fmat, NG4, DD, NG4, DD);
    // Bm = W_c[256:,:] @ W_w    (256 x 1024, K=256)
    gemm_nn<64,64,16><<<dim3(NG4/64, DD/64), blk, 0, stream>>>(
        W_c + (size_t)DD*DD, DD, W_w, NG4, nullptr, Bmw, NG4, DD, NG4, DD);
    // b2 = b_c @ W_w + b_w
    b2_kernel<<<dim3(NG4/256), blk, 0, stream>>>(b_c, W_w, b_w, B2);
    // fused persistent reader+writer
    fused_kernel<<<dim3(BB*WGB), blk, FUSED_LDS, stream>>>(
        XW, Fmat, Bmw, B2, U_r, U_w, x, HR, HWb, PMAX, PSUM, PM, flags, (float*)d_out);
}

// Round 4
// 4373.121 us; speedup vs baseline: 10.3070x; 1.0773x over previous
//
#include <hip/hip_runtime.h>
#include <math.h>

#define BB 8
#define LL 512
#define DD 256
#define NG4 1024
#define WGB 32     // WGs per batch
#define WR 16      // mem rows per WG
#define WU 8       // units per WG
#define MLD 264    // padded leading dim for mems tile

typedef __attribute__((ext_vector_type(4))) float f32x4;

// ---- workspace layout (float offsets) ----
static const size_t OFF_XW    = 0;
static const size_t OFF_F     = OFF_XW + (size_t)BB*LL*NG4;     // F = Wc_top @ Ww   (256x1024)
static const size_t OFF_BMW   = OFF_F + (size_t)DD*NG4;         // Bm = Wc_bot @ Ww  (256x1024)
static const size_t OFF_B2    = OFF_BMW + (size_t)DD*NG4;       // b2 = b_c@Ww + b_w (1024)
static const size_t OFF_HR    = OFF_B2 + NG4;                   // [2][B][256] h_r double buffer
static const size_t OFF_HW    = OFF_HR + (size_t)2*BB*DD;       // [B][256]   h_w
static const size_t OFF_PMAX  = OFF_HW + (size_t)BB*DD;         // [B][32]
static const size_t OFF_PSUM  = OFF_PMAX + (size_t)BB*WGB;      // [B][32]
static const size_t OFF_PM    = OFF_PSUM + (size_t)BB*WGB;      // [B][32][256]
static const size_t OFF_FLAGS = OFF_PM + (size_t)BB*WGB*DD;     // [B][32] u32 epochs
static const size_t TOTAL_WS  = OFF_FLAGS + BB*WGB;             // floats

__device__ __forceinline__ float hsig(float x) {
    return fminf(fmaxf(0.2f*x + 0.5f, 0.0f), 1.0f);
}

// coherent (bypass per-XCD L2) scalar access
__device__ __forceinline__ void st_coh(float* p, float v) {
    __hip_atomic_store(p, v, __ATOMIC_RELAXED, __HIP_MEMORY_SCOPE_AGENT);
}
__device__ __forceinline__ float ld_coh(const float* p) {
    return __hip_atomic_load(p, __ATOMIC_RELAXED, __HIP_MEMORY_SCOPE_AGENT);
}
__device__ __forceinline__ void st_coh_u(unsigned* p, unsigned v) {
    __hip_atomic_store(p, v, __ATOMIC_RELAXED, __HIP_MEMORY_SCOPE_AGENT);
}
__device__ __forceinline__ unsigned ld_coh_u(const unsigned* p) {
    return __hip_atomic_load(p, __ATOMIC_RELAXED, __HIP_MEMORY_SCOPE_AGENT);
}

// 8 coherent float4 loads, single drain at the end (pipelined at MALL)
__device__ __forceinline__ void ld_pm8(
    const f32x4* p0, const f32x4* p1, const f32x4* p2, const f32x4* p3,
    const f32x4* p4, const f32x4* p5, const f32x4* p6, const f32x4* p7,
    f32x4& a0, f32x4& a1, f32x4& a2, f32x4& a3,
    f32x4& a4, f32x4& a5, f32x4& a6, f32x4& a7)
{
    asm volatile(
        "global_load_dwordx4 %0, %8, off sc0 sc1\n\t"
        "global_load_dwordx4 %1, %9, off sc0 sc1\n\t"
        "global_load_dwordx4 %2, %10, off sc0 sc1\n\t"
        "global_load_dwordx4 %3, %11, off sc0 sc1\n\t"
        "global_load_dwordx4 %4, %12, off sc0 sc1\n\t"
        "global_load_dwordx4 %5, %13, off sc0 sc1\n\t"
        "global_load_dwordx4 %6, %14, off sc0 sc1\n\t"
        "global_load_dwordx4 %7, %15, off sc0 sc1\n\t"
        "s_waitcnt vmcnt(0)"
        : "=&v"(a0), "=&v"(a1), "=&v"(a2), "=&v"(a3),
          "=&v"(a4), "=&v"(a5), "=&v"(a6), "=&v"(a7)
        : "v"(p0), "v"(p1), "v"(p2), "v"(p3),
          "v"(p4), "v"(p5), "v"(p6), "v"(p7)
        : "memory");
}

// ---- simple fp32 tiled GEMM ----
template<int TM, int TN, int TK>
__global__ void __launch_bounds__(256) gemm_nn(
    const float* __restrict__ A, int lda,
    const float* __restrict__ Bmat, int ldb,
    const float* __restrict__ bias,
    float* __restrict__ C, int ldc,
    int M, int N, int K)
{
    __shared__ float As[TK][TM];
    __shared__ float Bs[TK][TN];
    const int m0 = blockIdx.y * TM, n0 = blockIdx.x * TN;
    const int tid = threadIdx.x;
    const int tx = tid % (TN/4);
    const int ty = tid / (TN/4);
    float acc[4][4] = {};
    for (int k0 = 0; k0 < K; k0 += TK) {
        {
            const int e = tid*4;
            const int m = e / TK, k = e % TK;
            const float4 v = *reinterpret_cast<const float4*>(&A[(size_t)(m0+m)*lda + k0 + k]);
            As[k+0][m] = v.x; As[k+1][m] = v.y; As[k+2][m] = v.z; As[k+3][m] = v.w;
        }
        {
            const int e = tid*4;
            const int k = e / TN, n = e % TN;
            const float4 v = *reinterpret_cast<const float4*>(&Bmat[(size_t)(k0+k)*ldb + n0 + n]);
            Bs[k][n+0] = v.x; Bs[k][n+1] = v.y; Bs[k][n+2] = v.z; Bs[k][n+3] = v.w;
        }
        __syncthreads();
        #pragma unroll
        for (int kk = 0; kk < TK; ++kk) {
            float a[4], bv[4];
            #pragma unroll
            for (int i = 0; i < 4; ++i) a[i] = As[kk][ty*4+i];
            #pragma unroll
            for (int j = 0; j < 4; ++j) bv[j] = Bs[kk][tx*4+j];
            #pragma unroll
            for (int i = 0; i < 4; ++i)
                #pragma unroll
                for (int j = 0; j < 4; ++j) acc[i][j] += a[i]*bv[j];
        }
        __syncthreads();
    }
    #pragma unroll
    for (int i = 0; i < 4; ++i) {
        const int m = m0 + ty*4 + i;
        #pragma unroll
        for (int j = 0; j < 4; ++j) {
            const int n = n0 + tx*4 + j;
            C[(size_t)m*ldc + n] = acc[i][j] + (bias ? bias[n] : 0.0f);
        }
    }
}

// b2[n] = b_w[n] + sum_k b_c[k]*W_w[k][n]
__global__ void __launch_bounds__(256) b2_kernel(
    const float* __restrict__ bc, const float* __restrict__ Ww,
    const float* __restrict__ bw, float* __restrict__ B2)
{
    const int n = blockIdx.x*256 + threadIdx.x;
    float a = bw[n];
    for (int k = 0; k < DD; ++k) a += bc[k]*Ww[(size_t)k*NG4 + n];
    B2[n] = a;
}

// ---- fused reader+writer persistent kernel (deep pipeline) ----
// Step s = 0..512, writer tau = s-1. Invariants entering step s:
//   LDS mems = mem_{s-3}; zp[] = z_{s-2} row weights; d1[r] = o_{s-1}.mem_{s-3}[r];
//   hr2[(s-1)&1] = h_r[s-1]; esx stale (overwritten at A).
// Phase A: load h_w(s-2); d2 = o.hw; scores via (1-zp)d1+zp*d2; softmax;
//   pm = sum w[r]*mem_old + beta*hw; store partials; flag1; mem update (hidden); poll.
// Phase B: batched loads (pms, pm, h_r[s], XW[s+1]); global softmax; m_rt;
//   z_w GEMV (hw@Uw + o@F + m@Bm + b2); h_w(s-1) gates+store;
//   reader h_r[s+1]; d1' = h_r[s].mem_{s-2}; flag2; poll.
__global__ void __launch_bounds__(256) fused_kernel(
    const float* __restrict__ XW, const float* __restrict__ Fw,
    const float* __restrict__ Bm, const float* __restrict__ B2,
    const float* __restrict__ Ur, const float* __restrict__ Uw,
    const float* __restrict__ x,
    float* __restrict__ HR, float* __restrict__ HWb,
    float* __restrict__ PMAX, float* __restrict__ PSUM, float* __restrict__ PM,
    unsigned* __restrict__ flags, float* __restrict__ out)
{
    extern __shared__ float sm[];
    float* Urs  = sm;              // [256][32]
    float* Uws  = Urs + 8192;      // [256][32]
    float* Fs   = Uws + 8192;      // [256][32]
    float* Bms  = Fs + 8192;       // [256][32]
    float* mems = Bms + 8192;      // [16][MLD]
    float* hr2  = mems + WR*MLD;   // [2][256] h_r parity slots
    float* hw   = hr2 + 512;       // 256
    float* ms   = hw + 256;        // 256
    float* zredR= ms + 256;        // 256
    float* zredW= zredR + 256;     // 256
    float* red4 = zredW + 256;     // [4][256]
    float* xws  = red4 + 1024;     // 32
    float* b2s  = xws + 32;        // 32
    float* zrs  = b2s + 32;        // 32
    float* zws  = zrs + 32;        // 32
    float* fwS  = zws + 32;        // 32
    float* d1   = fwS + 32;        // 16
    float* zp   = d1 + 16;         // 16
    float* esx  = zp + 16;         // 16
    float* wv   = esx + 16;        // 16
    float* wsum = wv + 16;         // 8 (use 4)
    float* cr   = wsum + 8;        // 8
    float* cw   = cr + 8;          // 8
    float* misc = cw + 8;          // [0]=scale, [1]=invS, [2]=beta

    const int b   = (int)blockIdx.x & 7;    // team -> same XCD (heuristic)
    const int wg  = (int)blockIdx.x >> 3;   // 0..31
    const int tid = threadIdx.x;
    const int R0  = wg*WR;
    const int U0  = wg*WU;
    const int gc32 = (tid>>3)*DD + U0 + (tid&7);   // global col for lane<32

    // --- init: weight slices ---
    for (int it = 0; it < 32; ++it) {
        const int e = it*256 + tid;
        const int k = e >> 5, cl = e & 31;
        const int gc = (cl>>3)*DD + U0 + (cl&7);
        Urs[k*32+cl] = Ur[(size_t)k*NG4 + gc];
        Uws[k*32+cl] = Uw[(size_t)k*NG4 + gc];
        Fs [k*32+cl] = Fw[(size_t)k*NG4 + gc];
        Bms[k*32+cl] = Bm[(size_t)k*NG4 + gc];
    }
    if (tid < 32) b2s[tid] = B2[gc32];
    for (int r = 0; r < WR; ++r)
        mems[r*MLD + tid] = x[((size_t)b*LL + R0 + r)*DD + tid];
    // prologue: full h_r[0] computed locally (h=0 -> z = XW row 0)
    {
        const size_t base = (size_t)b*LL*NG4;
        const float zi = XW[base + tid];
        const float zg = XW[base + 512 + tid];
        const float zo = XW[base + 768 + tid];
        const float c0 = hsig(zi)*tanhf(zg);
        hr2[tid] = hsig(zo)*tanhf(c0);
        hr2[256 + tid] = 0.f;
        if (tid >= U0 && tid < U0+WU) cr[tid-U0] = c0;
    }
    if (tid < 16) { zp[tid] = 0.f; d1[tid] = 0.f; esx[tid] = 0.f; }
    if (tid < 8)  cw[tid] = 0.f;
    if (tid < 4)  misc[tid] = 0.f;
    __syncthreads();

    unsigned* flb = flags + b*WGB;

    for (int s = 0; s <= LL; ++s) {
        const bool doW = (s >= 1);
        float* hrN_s = hr2 + (s&1)*256;        // h_r[s]
        float* hrO_s = hr2 + ((s+1)&1)*256;    // h_r[s-1] = o_tau

        // ================= PHASE A =================
        float hw_r = 0.f;
        if (s >= 2) hw_r = ld_coh(&HWb[b*DD + tid]);   // h_w(s-2)
        hw[tid] = hw_r;
        __syncthreads();

        // d2 = o_tau . h_w  (full-wave reduce)
        {
            float v = hrO_s[tid]*hw_r;
            #pragma unroll
            for (int off = 32; off; off >>= 1) v += __shfl_xor(v, off);
            if ((tid & 63) == 0) wsum[tid>>6] = v;
        }
        __syncthreads();

        if (doW && tid < 16) {
            const float d2v = wsum[0]+wsum[1]+wsum[2]+wsum[3];
            const float zpv = zp[tid];
            const float sc  = (1.f - zpv)*d1[tid] + zpv*d2v;
            float m = sc;
            #pragma unroll
            for (int off = 8; off; off >>= 1) m = fmaxf(m, __shfl_xor(m, off, 16));
            const float e = __expf(sc - m);
            esx[tid] = e;
            wv[tid]  = e*(1.f - zpv);
            float sum = e, bp = e*zpv;
            #pragma unroll
            for (int off = 8; off; off >>= 1) {
                sum += __shfl_xor(sum, off, 16);
                bp  += __shfl_xor(bp,  off, 16);
            }
            if (tid == 0) {
                misc[2] = bp;
                st_coh(&PMAX[b*WGB + wg], m);
                st_coh(&PSUM[b*WGB + wg], sum);
            }
        }
        __syncthreads();

        if (doW) {   // pm partial over mem_{s-2} via decomposition (mems = mem_{s-3})
            float p = misc[2]*hw_r;
            #pragma unroll
            for (int r = 0; r < WR; ++r) p += wv[r]*mems[r*MLD + tid];
            st_coh(&PM[((size_t)b*WGB + wg)*DD + tid], p);
        }

        // barrier1 with hidden mem update
        asm volatile("s_waitcnt vmcnt(0)" ::: "memory");
        __syncthreads();
        if (tid == 0) st_coh_u(&flb[wg], 2u*(unsigned)s + 1u);
        if (s >= 2) {    // mem_{s-3} -> mem_{s-2} (hidden behind poll)
            #pragma unroll
            for (int r = 0; r < WR; ++r) {
                const float z = zp[r];
                float* mp = &mems[r*MLD + tid];
                *mp = *mp*(1.f - z) + hw_r*z;
            }
        }
        if (tid < 64) {
            const unsigned target = 2u*(unsigned)s + 1u;
            unsigned v;
            do { v = ld_coh_u(&flb[tid & 31]); } while (!__all(v >= target));
        }
        __syncthreads();

        // ================= PHASE B =================
        // batched loads: h_r[s], XW[s+1], pms, pm
        float hrN_r = 0.f;
        if (s >= 1 && s <= 511) hrN_r = ld_coh(&HR[((size_t)(s&1))*BB*DD + b*DD + tid]);
        float xw_r = 0.f;
        if (s <= 510 && tid < 32) xw_r = XW[((size_t)b*LL + s + 1)*NG4 + gc32];
        float pmx_r = 0.f, ps_r = 0.f;
        if (doW && tid < 32) {
            pmx_r = ld_coh(&PMAX[b*WGB + tid]);
            ps_r  = ld_coh(&PSUM[b*WGB + tid]);
        }
        f32x4 a0,a1,a2,a3,a4,a5,a6,a7;
        const int w0 = tid >> 6, dq = tid & 63;
        if (doW) {
            const float* pmb = PM + (size_t)b*WGB*DD;
            ld_pm8((const f32x4*)(pmb + (w0+ 0)*DD) + dq, (const f32x4*)(pmb + (w0+ 4)*DD) + dq,
                   (const f32x4*)(pmb + (w0+ 8)*DD) + dq, (const f32x4*)(pmb + (w0+12)*DD) + dq,
                   (const f32x4*)(pmb + (w0+16)*DD) + dq, (const f32x4*)(pmb + (w0+20)*DD) + dq,
                   (const f32x4*)(pmb + (w0+24)*DD) + dq, (const f32x4*)(pmb + (w0+28)*DD) + dq,
                   a0,a1,a2,a3,a4,a5,a6,a7);
        }
        if (s >= 1 && s <= 511) hrN_s[tid] = hrN_r;
        if (s <= 510 && tid < 32) xws[tid] = xw_r;
        __syncthreads();

        if (doW) {
            // global softmax weights
            if (tid < 32) {
                float g = pmx_r;
                #pragma unroll
                for (int off = 16; off; off >>= 1) g = fmaxf(g, __shfl_xor(g, off, 32));
                const float fw = __expf(pmx_r - g);
                float S = ps_r*fw;
                #pragma unroll
                for (int off = 16; off; off >>= 1) S += __shfl_xor(S, off, 32);
                fwS[tid] = fw;
                if (tid == 0)  misc[1] = 1.f/S;
                if (tid == wg) misc[0] = fw/S;
            }
            __syncthreads();
            // m_rt combine
            {
                f32x4 acc = a0*fwS[w0];
                acc += a1*fwS[w0+4];  acc += a2*fwS[w0+8];
                acc += a3*fwS[w0+12]; acc += a4*fwS[w0+16];
                acc += a5*fwS[w0+20]; acc += a6*fwS[w0+24];
                acc += a7*fwS[w0+28];
                *(f32x4*)(red4 + w0*DD + dq*4) = acc;
            }
            __syncthreads();
            ms[tid] = (red4[tid] + red4[DD+tid] + red4[2*DD+tid] + red4[3*DD+tid]) * misc[1];
            if (tid < 16) zp[tid] = esx[tid]*misc[0];   // z_{s-1} for next step
            __syncthreads();
            // z_w GEMV: hw@Uw + o@F + m@Bm
            {
                const int kc = tid >> 5, cl = tid & 31, k0 = kc*32;
                float a = 0.f;
                #pragma unroll 8
                for (int k = k0; k < k0+32; ++k)
                    a += hw[k]*Uws[k*32+cl] + hrO_s[k]*Fs[k*32+cl] + ms[k]*Bms[k*32+cl];
                zredW[tid] = a;
            }
            __syncthreads();
            if (tid < 32) {
                float z = b2s[tid];
                #pragma unroll
                for (int q = 0; q < 8; ++q) z += zredW[q*32 + tid];
                zws[tid] = z;
            }
            __syncthreads();
            if (tid < 8) {
                const float ig = hsig(zws[tid]);
                const float fg = hsig(zws[8+tid]);
                const float gg = tanhf(zws[16+tid]);
                const float og = hsig(zws[24+tid]);
                const float c  = fg*cw[tid] + ig*gg;
                cw[tid] = c;
                const float h = og*tanhf(c);
                st_coh(&HWb[b*DD + U0 + tid], h);
                if (s == LL) out[b*DD + U0 + tid] = h;
            }
        }

        // reader: h_r[s+1] from h_r[s]
        if (s <= 510) {
            const int kc = tid >> 5, cl = tid & 31, k0 = kc*32;
            float a = 0.f;
            #pragma unroll 8
            for (int k = k0; k < k0+32; ++k) a += hrN_s[k]*Urs[k*32+cl];
            zredR[tid] = a;
        }
        __syncthreads();
        if (s <= 510 && tid < 32) {
            float z = xws[tid];
            #pragma unroll
            for (int q = 0; q < 8; ++q) z += zredR[q*32 + tid];
            zrs[tid] = z;
        }
        __syncthreads();
        if (s <= 510 && tid < 8) {
            const float ig = hsig(zrs[tid]);
            const float fg = hsig(zrs[8+tid]);
            const float gg = tanhf(zrs[16+tid]);
            const float og = hsig(zrs[24+tid]);
            const float c  = fg*cr[tid] + ig*gg;
            cr[tid] = c;
            st_coh(&HR[((size_t)((s+1)&1))*BB*DD + b*DD + U0 + tid], og*tanhf(c));
        }
        // d1' = h_r[s] . mem_{s-2}  (for next step's scores)
        if (s < LL) {
            const int r = tid >> 4, j = tid & 15;
            float a = 0.f;
            const float* mrow = mems + r*MLD;
            #pragma unroll 4
            for (int d = j; d < DD; d += 16) a += hrN_s[d]*mrow[d];
            #pragma unroll
            for (int off = 8; off; off >>= 1) a += __shfl_down(a, off, 16);
            if (j == 0) d1[r] = a;
        }

        if (s < LL) {   // barrier2
            asm volatile("s_waitcnt vmcnt(0)" ::: "memory");
            __syncthreads();
            if (tid == 0) st_coh_u(&flb[wg], 2u*(unsigned)s + 2u);
            if (tid < 64) {
                const unsigned target = 2u*(unsigned)s + 2u;
                unsigned v;
                do { v = ld_coh_u(&flb[tid & 31]); } while (!__all(v >= target));
            }
            __syncthreads();
        }
    }
}

extern "C" void kernel_launch(void* const* d_in, const int* in_sizes, int n_in,
                              void* d_out, int out_size, void* d_ws, size_t ws_size,
                              hipStream_t stream) {
    const float* x   = (const float*)d_in[0];
    const float* W_r = (const float*)d_in[1];
    const float* U_r = (const float*)d_in[2];
    const float* b_r = (const float*)d_in[3];
    const float* W_w = (const float*)d_in[4];
    const float* U_w = (const float*)d_in[5];
    const float* b_w = (const float*)d_in[6];
    const float* W_c = (const float*)d_in[7];
    const float* b_c = (const float*)d_in[8];
    (void)in_sizes; (void)n_in;

    if (ws_size < TOTAL_WS * sizeof(float)) return;

    float* ws   = (float*)d_ws;
    float* XW   = ws + OFF_XW;
    float* Fmat = ws + OFF_F;
    float* Bmw  = ws + OFF_BMW;
    float* B2   = ws + OFF_B2;
    float* HR   = ws + OFF_HR;
    float* HWb  = ws + OFF_HW;
    float* PMAX = ws + OFF_PMAX;
    float* PSUM = ws + OFF_PSUM;
    float* PM   = ws + OFF_PM;
    unsigned* flags = (unsigned*)(ws + OFF_FLAGS);

    const int FUSED_LDS = 39808 * 4;   // 159232 B
    hipFuncSetAttribute((const void*)fused_kernel, hipFuncAttributeMaxDynamicSharedMemorySize, FUSED_LDS);

    hipMemsetAsync(flags, 0, BB*WGB*sizeof(unsigned), stream);

    dim3 blk(256);
    // XW = x @ W_r + b_r        (4096 x 1024, K=256)
    gemm_nn<64,64,16><<<dim3(NG4/64, (BB*LL)/64), blk, 0, stream>>>(
        x, DD, W_r, NG4, b_r, XW, NG4, BB*LL, NG4, DD);
    // F  = W_c[:256,:] @ W_w    (256 x 1024, K=256)
    gemm_nn<64,64,16><<<dim3(NG4/64, DD/64), blk, 0, stream>>>(
        W_c, DD, W_w, NG4, nullptr, Fmat, NG4, DD, NG4, DD);
    // Bm = W_c[256:,:] @ W_w    (256 x 1024, K=256)
    gemm_nn<64,64,16><<<dim3(NG4/64, DD/64), blk, 0, stream>>>(
        W_c + (size_t)DD*DD, DD, W_w, NG4, nullptr, Bmw, NG4, DD, NG4, DD);
    // b2 = b_c @ W_w + b_w
    b2_kernel<<<dim3(NG4/256), blk, 0, stream>>>(b_c, W_w, b_w, B2);
    // fused persistent reader+writer (deep pipeline)
    fused_kernel<<<dim3(BB*WGB), blk, FUSED_LDS, stream>>>(
        XW, Fmat, Bmw, B2, U_r, U_w, x, HR, HWb, PMAX, PSUM, PM, flags, (float*)d_out);
}

// Round 5
// 3983.615 us; speedup vs baseline: 11.3147x; 1.0978x over previous
//
#include <hip/hip_runtime.h>
#include <math.h>

#define BB 8
#define LL 512
#define DD 256
#define NG4 1024
#define WGB 32     // WGs per batch
#define WR 16      // mem rows per WG
#define WU 8       // units per WG
#define MLD 264    // padded leading dim for mems tile

typedef __attribute__((ext_vector_type(4))) float f32x4;

// ---- workspace layout (float offsets) ----
static const size_t OFF_XW    = 0;
static const size_t OFF_F     = OFF_XW + (size_t)BB*LL*NG4;     // F = Wc_top @ Ww   (256x1024)
static const size_t OFF_BMW   = OFF_F + (size_t)DD*NG4;         // Bm = Wc_bot @ Ww  (256x1024)
static const size_t OFF_B2    = OFF_BMW + (size_t)DD*NG4;       // b2 = b_c@Ww + b_w (1024)
static const size_t OFF_HR    = OFF_B2 + NG4;                   // [2][B][256] h_r double buffer
static const size_t OFF_HW    = OFF_HR + (size_t)2*BB*DD;       // [B][256]   h_w
static const size_t OFF_PMAX  = OFF_HW + (size_t)BB*DD;         // [B][32]
static const size_t OFF_PSUM  = OFF_PMAX + (size_t)BB*WGB;      // [B][32]
static const size_t OFF_RHO   = OFF_PSUM + (size_t)BB*WGB;      // [B][32] rho partial dots
static const size_t OFF_PM    = OFF_RHO + (size_t)BB*WGB;       // [B][32][256]
static const size_t OFF_FLAGS = OFF_PM + (size_t)BB*WGB*DD;     // [B] u32 counters, 32-stride padded
static const size_t TOTAL_WS  = OFF_FLAGS + BB*32;              // floats

__device__ __forceinline__ float hsig(float x) {
    return fminf(fmaxf(0.2f*x + 0.5f, 0.0f), 1.0f);
}

// coherent (bypass per-XCD L2) scalar access
__device__ __forceinline__ void st_coh(float* p, float v) {
    __hip_atomic_store(p, v, __ATOMIC_RELAXED, __HIP_MEMORY_SCOPE_AGENT);
}
__device__ __forceinline__ float ld_coh(const float* p) {
    return __hip_atomic_load(p, __ATOMIC_RELAXED, __HIP_MEMORY_SCOPE_AGENT);
}
__device__ __forceinline__ unsigned ld_coh_u(const unsigned* p) {
    return __hip_atomic_load(p, __ATOMIC_RELAXED, __HIP_MEMORY_SCOPE_AGENT);
}

// 8 coherent float4 loads, single drain at the end (pipelined at MALL)
__device__ __forceinline__ void ld_pm8(
    const f32x4* p0, const f32x4* p1, const f32x4* p2, const f32x4* p3,
    const f32x4* p4, const f32x4* p5, const f32x4* p6, const f32x4* p7,
    f32x4& a0, f32x4& a1, f32x4& a2, f32x4& a3,
    f32x4& a4, f32x4& a5, f32x4& a6, f32x4& a7)
{
    asm volatile(
        "global_load_dwordx4 %0, %8, off sc0 sc1\n\t"
        "global_load_dwordx4 %1, %9, off sc0 sc1\n\t"
        "global_load_dwordx4 %2, %10, off sc0 sc1\n\t"
        "global_load_dwordx4 %3, %11, off sc0 sc1\n\t"
        "global_load_dwordx4 %4, %12, off sc0 sc1\n\t"
        "global_load_dwordx4 %5, %13, off sc0 sc1\n\t"
        "global_load_dwordx4 %6, %14, off sc0 sc1\n\t"
        "global_load_dwordx4 %7, %15, off sc0 sc1\n\t"
        "s_waitcnt vmcnt(0)"
        : "=&v"(a0), "=&v"(a1), "=&v"(a2), "=&v"(a3),
          "=&v"(a4), "=&v"(a5), "=&v"(a6), "=&v"(a7)
        : "v"(p0), "v"(p1), "v"(p2), "v"(p3),
          "v"(p4), "v"(p5), "v"(p6), "v"(p7)
        : "memory");
}

// ---- simple fp32 tiled GEMM ----
template<int TM, int TN, int TK>
__global__ void __launch_bounds__(256) gemm_nn(
    const float* __restrict__ A, int lda,
    const float* __restrict__ Bmat, int ldb,
    const float* __restrict__ bias,
    float* __restrict__ C, int ldc,
    int M, int N, int K)
{
    __shared__ float As[TK][TM];
    __shared__ float Bs[TK][TN];
    const int m0 = blockIdx.y * TM, n0 = blockIdx.x * TN;
    const int tid = threadIdx.x;
    const int tx = tid % (TN/4);
    const int ty = tid / (TN/4);
    float acc[4][4] = {};
    for (int k0 = 0; k0 < K; k0 += TK) {
        {
            const int e = tid*4;
            const int m = e / TK, k = e % TK;
            const float4 v = *reinterpret_cast<const float4*>(&A[(size_t)(m0+m)*lda + k0 + k]);
            As[k+0][m] = v.x; As[k+1][m] = v.y; As[k+2][m] = v.z; As[k+3][m] = v.w;
        }
        {
            const int e = tid*4;
            const int k = e / TN, n = e % TN;
            const float4 v = *reinterpret_cast<const float4*>(&Bmat[(size_t)(k0+k)*ldb + n0 + n]);
            Bs[k][n+0] = v.x; Bs[k][n+1] = v.y; Bs[k][n+2] = v.z; Bs[k][n+3] = v.w;
        }
        __syncthreads();
        #pragma unroll
        for (int kk = 0; kk < TK; ++kk) {
            float a[4], bv[4];
            #pragma unroll
            for (int i = 0; i < 4; ++i) a[i] = As[kk][ty*4+i];
            #pragma unroll
            for (int j = 0; j < 4; ++j) bv[j] = Bs[kk][tx*4+j];
            #pragma unroll
            for (int i = 0; i < 4; ++i)
                #pragma unroll
                for (int j = 0; j < 4; ++j) acc[i][j] += a[i]*bv[j];
        }
        __syncthreads();
    }
    #pragma unroll
    for (int i = 0; i < 4; ++i) {
        const int m = m0 + ty*4 + i;
        #pragma unroll
        for (int j = 0; j < 4; ++j) {
            const int n = n0 + tx*4 + j;
            C[(size_t)m*ldc + n] = acc[i][j] + (bias ? bias[n] : 0.0f);
        }
    }
}

// b2[n] = b_w[n] + sum_k b_c[k]*W_w[k][n]
__global__ void __launch_bounds__(256) b2_kernel(
    const float* __restrict__ bc, const float* __restrict__ Ww,
    const float* __restrict__ bw, float* __restrict__ B2)
{
    const int n = blockIdx.x*256 + threadIdx.x;
    float a = bw[n];
    for (int k = 0; k < DD; ++k) a += bc[k]*Ww[(size_t)k*NG4 + n];
    B2[n] = a;
}

// ---- fused reader+writer persistent kernel ----
// Same dataflow as round 4 (validated), rescheduled:
//  - d2 from RHO scalar partials (published with h_w slices) -> parallel with h_w load
//  - hw@Uw + o@F GEMV moved into barrier-1 hidden region
//  - XW prefetch issued at top of phase A (completes inside barrier-1 drain)
//  - single padded counter per batch, 1 polling lane, s_sleep between polls
__global__ void __launch_bounds__(256) fused_kernel(
    const float* __restrict__ XW, const float* __restrict__ Fw,
    const float* __restrict__ Bm, const float* __restrict__ B2,
    const float* __restrict__ Ur, const float* __restrict__ Uw,
    const float* __restrict__ x,
    float* __restrict__ HR, float* __restrict__ HWb,
    float* __restrict__ PMAX, float* __restrict__ PSUM, float* __restrict__ RHO,
    float* __restrict__ PM,
    unsigned* __restrict__ flags, float* __restrict__ out)
{
    extern __shared__ float sm[];
    float* Urs  = sm;              // [256][32]
    float* Uws  = Urs + 8192;      // [256][32]
    float* Fs   = Uws + 8192;      // [256][32]
    float* Bms  = Fs + 8192;       // [256][32]
    float* mems = Bms + 8192;      // [16][MLD]
    float* hr2  = mems + WR*MLD;   // [2][256] h_r parity slots
    float* hw   = hr2 + 512;       // 256
    float* ms   = hw + 256;        // 256
    float* zredR= ms + 256;        // 256
    float* zredW= zredR + 256;     // 256
    float* red4 = zredW + 256;     // [4][256]
    float* xws  = red4 + 1024;     // 32
    float* b2s  = xws + 32;        // 32
    float* zrs  = b2s + 32;        // 32
    float* zws  = zrs + 32;        // 32
    float* fwS  = zws + 32;        // 32
    float* d1   = fwS + 32;        // 16
    float* zp   = d1 + 16;         // 16
    float* esx  = zp + 16;         // 16
    float* wv   = esx + 16;        // 16
    float* cr   = wv + 16;         // 8
    float* cw   = cr + 8;          // 8
    float* misc = cw + 8;          // [0]=scale, [1]=invS, [2]=beta

    const int b   = (int)blockIdx.x & 7;    // team -> same XCD (heuristic)
    const int wg  = (int)blockIdx.x >> 3;   // 0..31
    const int tid = threadIdx.x;
    const int R0  = wg*WR;
    const int U0  = wg*WU;
    const int gc32 = (tid>>3)*DD + U0 + (tid&7);   // global col for lane<32

    // --- init: weight slices ---
    for (int it = 0; it < 32; ++it) {
        const int e = it*256 + tid;
        const int k = e >> 5, cl = e & 31;
        const int gc = (cl>>3)*DD + U0 + (cl&7);
        Urs[k*32+cl] = Ur[(size_t)k*NG4 + gc];
        Uws[k*32+cl] = Uw[(size_t)k*NG4 + gc];
        Fs [k*32+cl] = Fw[(size_t)k*NG4 + gc];
        Bms[k*32+cl] = Bm[(size_t)k*NG4 + gc];
    }
    if (tid < 32) b2s[tid] = B2[gc32];
    for (int r = 0; r < WR; ++r)
        mems[r*MLD + tid] = x[((size_t)b*LL + R0 + r)*DD + tid];
    // prologue: full h_r[0] computed locally (h=0 -> z = XW row 0)
    {
        const size_t base = (size_t)b*LL*NG4;
        const float zi = XW[base + tid];
        const float zg = XW[base + 512 + tid];
        const float zo = XW[base + 768 + tid];
        const float c0 = hsig(zi)*tanhf(zg);
        hr2[tid] = hsig(zo)*tanhf(c0);
        hr2[256 + tid] = 0.f;
        if (tid >= U0 && tid < U0+WU) cr[tid-U0] = c0;
    }
    if (tid < 16) { zp[tid] = 0.f; d1[tid] = 0.f; esx[tid] = 0.f; }
    if (tid < 8)  cw[tid] = 0.f;
    if (tid < 4)  misc[tid] = 0.f;
    __syncthreads();

    unsigned* flb = &flags[b*32];

    for (int s = 0; s <= LL; ++s) {
        const bool doW = (s >= 1);
        float* hrN_s = hr2 + (s&1)*256;        // h_r[s]
        float* hrO_s = hr2 + ((s+1)&1)*256;    // h_r[s-1] = o_tau

        // ================= PHASE A (writer tau = s-1 partials) =================
        // XW prefetch for reader step s+1: HBM-latency absorbed by barrier-1 drain
        float xw_r = 0.f;
        if (s <= LL-2 && tid < 32) xw_r = XW[((size_t)b*LL + s + 1)*NG4 + gc32];
        float hw_r = 0.f, rho_r = 0.f;
        if (s >= 2) {
            hw_r = ld_coh(&HWb[b*DD + tid]);                 // h_w(s-2)
            if (tid < 32) rho_r = ld_coh(&RHO[b*WGB + tid]); // slice dots o_{s-1}.h_w(s-2)
        }
        hw[tid] = hw_r;

        // d2 from rho partials + local softmax (wave 0 only, no syncthreads inside)
        if (tid < 32) {
            float d2 = rho_r;
            #pragma unroll
            for (int off = 16; off; off >>= 1) d2 += __shfl_xor(d2, off, 32);
            if (doW && tid < 16) {
                const float zpv = zp[tid];
                const float sc  = (1.f - zpv)*d1[tid] + zpv*d2;
                float m = sc;
                #pragma unroll
                for (int off = 8; off; off >>= 1) m = fmaxf(m, __shfl_xor(m, off, 16));
                const float e = __expf(sc - m);
                esx[tid] = e;
                wv[tid]  = e*(1.f - zpv);
                float sum = e, bp = e*zpv;
                #pragma unroll
                for (int off = 8; off; off >>= 1) {
                    sum += __shfl_xor(sum, off, 16);
                    bp  += __shfl_xor(bp,  off, 16);
                }
                if (tid == 0) {
                    misc[2] = bp;
                    st_coh(&PMAX[b*WGB + wg], m);
                    st_coh(&PSUM[b*WGB + wg], sum);
                }
            }
        }
        __syncthreads();   // wv, misc[2], hw visible

        if (doW) {   // pm partial over mem_{s-2} (mems holds mem_{s-3})
            float p = misc[2]*hw_r;
            #pragma unroll
            for (int r = 0; r < WR; ++r) p += wv[r]*mems[r*MLD + tid];
            st_coh(&PM[((size_t)b*WGB + wg)*DD + tid], p);
        }

        // --- barrier 1: drain, count, hidden work, poll ---
        asm volatile("s_waitcnt vmcnt(0)" ::: "memory");
        __syncthreads();
        if (tid == 0)
            __hip_atomic_fetch_add(flb, 1u, __ATOMIC_RELAXED, __HIP_MEMORY_SCOPE_AGENT);
        if (s >= 2) {    // mem_{s-3} -> mem_{s-2} (hidden)
            #pragma unroll
            for (int r = 0; r < WR; ++r) {
                const float z = zp[r];
                float* mp = &mems[r*MLD + tid];
                *mp = *mp*(1.f - z) + hw_r*z;
            }
        }
        if (doW) {       // hw@Uw + o@F GEMV partial (hidden)
            const int kc = tid >> 5, cl = tid & 31, k0 = kc*32;
            float a = 0.f;
            #pragma unroll 8
            for (int k = k0; k < k0+32; ++k)
                a += hw[k]*Uws[k*32+cl] + hrO_s[k]*Fs[k*32+cl];
            zredW[tid] = a;
        }
        if (tid == 0) {
            const unsigned target = 64u*(unsigned)s + 32u;
            while (ld_coh_u(flb) < target) __builtin_amdgcn_s_sleep(1);
        }
        __syncthreads();

        // ================= PHASE B =================
        // batched coherent loads: h_r[s], pms, pm partials
        float hrN_r = 0.f;
        if (s >= 1 && s <= LL-1) hrN_r = ld_coh(&HR[((size_t)(s&1))*BB*DD + b*DD + tid]);
        float pmx_r = 0.f, ps_r = 0.f;
        if (doW && tid < 32) {
            pmx_r = ld_coh(&PMAX[b*WGB + tid]);
            ps_r  = ld_coh(&PSUM[b*WGB + tid]);
        }
        f32x4 a0,a1,a2,a3,a4,a5,a6,a7;
        const int w0 = tid >> 6, dq = tid & 63;
        if (doW) {
            const float* pmb = PM + (size_t)b*WGB*DD;
            ld_pm8((const f32x4*)(pmb + (w0+ 0)*DD) + dq, (const f32x4*)(pmb + (w0+ 4)*DD) + dq,
                   (const f32x4*)(pmb + (w0+ 8)*DD) + dq, (const f32x4*)(pmb + (w0+12)*DD) + dq,
                   (const f32x4*)(pmb + (w0+16)*DD) + dq, (const f32x4*)(pmb + (w0+20)*DD) + dq,
                   (const f32x4*)(pmb + (w0+24)*DD) + dq, (const f32x4*)(pmb + (w0+28)*DD) + dq,
                   a0,a1,a2,a3,a4,a5,a6,a7);
        }
        if (s >= 1 && s <= LL-1) hrN_s[tid] = hrN_r;
        if (s <= LL-2 && tid < 32) xws[tid] = xw_r;
        __syncthreads();   // S1: hrN, xws visible

        if (doW && tid < 32) {   // global softmax weights
            float g = pmx_r;
            #pragma unroll
            for (int off = 16; off; off >>= 1) g = fmaxf(g, __shfl_xor(g, off, 32));
            const float fw = __expf(pmx_r - g);
            float S = ps_r*fw;
            #pragma unroll
            for (int off = 16; off; off >>= 1) S += __shfl_xor(S, off, 32);
            fwS[tid] = fw;
            if (tid == 0)  misc[1] = 1.f/S;
            if (tid == wg) misc[0] = fw/S;
        }
        if (s <= LL-2) {   // reader GEMV partial
            const int kc = tid >> 5, cl = tid & 31, k0 = kc*32;
            float a = 0.f;
            #pragma unroll 8
            for (int k = k0; k < k0+32; ++k) a += hrN_s[k]*Urs[k*32+cl];
            zredR[tid] = a;
        }
        __syncthreads();   // S2: fwS, misc, zredR visible

        if (doW) {
            // m_rt combine
            f32x4 acc = a0*fwS[w0];
            acc += a1*fwS[w0+4];  acc += a2*fwS[w0+8];
            acc += a3*fwS[w0+12]; acc += a4*fwS[w0+16];
            acc += a5*fwS[w0+20]; acc += a6*fwS[w0+24];
            acc += a7*fwS[w0+28];
            *(f32x4*)(red4 + w0*DD + dq*4) = acc;
        }
        __syncthreads();   // S3: red4 visible
        if (doW) {
            ms[tid] = (red4[tid] + red4[DD+tid] + red4[2*DD+tid] + red4[3*DD+tid]) * misc[1];
            if (tid < 16) zp[tid] = esx[tid]*misc[0];   // z_{s-1} for next step
        }
        __syncthreads();   // S4: ms visible
        if (doW) {         // += ms@Bm  (zredW already holds hw@Uw + o@F)
            const int kc = tid >> 5, cl = tid & 31, k0 = kc*32;
            float a = zredW[tid];
            #pragma unroll 8
            for (int k = k0; k < k0+32; ++k) a += ms[k]*Bms[k*32+cl];
            zredW[tid] = a;
        }
        __syncthreads();   // S5
        if (tid < 32) {
            if (doW) {
                float z = b2s[tid];
                #pragma unroll
                for (int q = 0; q < 8; ++q) z += zredW[q*32 + tid];
                zws[tid] = z;
            }
            if (s <= LL-2) {
                float z = xws[tid];
                #pragma unroll
                for (int q = 0; q < 8; ++q) z += zredR[q*32 + tid];
                zrs[tid] = z;
            }
        }
        __syncthreads();   // S6: zws, zrs visible

        if (doW && tid < 8) {   // writer gates + h_w slice + rho partial
            const float ig = hsig(zws[tid]);
            const float fg = hsig(zws[8+tid]);
            const float gg = tanhf(zws[16+tid]);
            const float og = hsig(zws[24+tid]);
            const float c  = fg*cw[tid] + ig*gg;
            cw[tid] = c;
            const float h = og*tanhf(c);
            st_coh(&HWb[b*DD + U0 + tid], h);
            if (s < LL) {
                float rr = h * hrN_s[U0 + tid];    // o_s . h_w(s-1), own slice
                rr += __shfl_down(rr, 4, 8);
                rr += __shfl_down(rr, 2, 8);
                rr += __shfl_down(rr, 1, 8);
                if (tid == 0) st_coh(&RHO[b*WGB + wg], rr);
            }
            if (s == LL) out[b*DD + U0 + tid] = h;
        }
        if (s <= LL-2 && tid < 8) {   // reader gates + h_r[s+1] slice
            const float ig = hsig(zrs[tid]);
            const float fg = hsig(zrs[8+tid]);
            const float gg = tanhf(zrs[16+tid]);
            const float og = hsig(zrs[24+tid]);
            const float c  = fg*cr[tid] + ig*gg;
            cr[tid] = c;
            st_coh(&HR[((size_t)((s+1)&1))*BB*DD + b*DD + U0 + tid], og*tanhf(c));
        }

        // --- barrier 2: drain, count, hidden d1', poll ---
        if (s < LL) {
            asm volatile("s_waitcnt vmcnt(0)" ::: "memory");
            __syncthreads();
            if (tid == 0)
                __hip_atomic_fetch_add(flb, 1u, __ATOMIC_RELAXED, __HIP_MEMORY_SCOPE_AGENT);
            {   // d1' = h_r[s] . mem rows (hidden)
                const int r = tid >> 4, j = tid & 15;
                float a = 0.f;
                const float* mrow = mems + r*MLD;
                #pragma unroll 4
                for (int d = j; d < DD; d += 16) a += hrN_s[d]*mrow[d];
                #pragma unroll
                for (int off = 8; off; off >>= 1) a += __shfl_down(a, off, 16);
                if (j == 0) d1[r] = a;
            }
            if (tid == 0) {
                const unsigned target = 64u*(unsigned)s + 64u;
                while (ld_coh_u(flb) < target) __builtin_amdgcn_s_sleep(1);
            }
            __syncthreads();
        }
    }
}

extern "C" void kernel_launch(void* const* d_in, const int* in_sizes, int n_in,
                              void* d_out, int out_size, void* d_ws, size_t ws_size,
                              hipStream_t stream) {
    const float* x   = (const float*)d_in[0];
    const float* W_r = (const float*)d_in[1];
    const float* U_r = (const float*)d_in[2];
    const float* b_r = (const float*)d_in[3];
    const float* W_w = (const float*)d_in[4];
    const float* U_w = (const float*)d_in[5];
    const float* b_w = (const float*)d_in[6];
    const float* W_c = (const float*)d_in[7];
    const float* b_c = (const float*)d_in[8];
    (void)in_sizes; (void)n_in;

    if (ws_size < TOTAL_WS * sizeof(float)) return;

    float* ws   = (float*)d_ws;
    float* XW   = ws + OFF_XW;
    float* Fmat = ws + OFF_F;
    float* Bmw  = ws + OFF_BMW;
    float* B2   = ws + OFF_B2;
    float* HR   = ws + OFF_HR;
    float* HWb  = ws + OFF_HW;
    float* PMAX = ws + OFF_PMAX;
    float* PSUM = ws + OFF_PSUM;
    float* RHO  = ws + OFF_RHO;
    float* PM   = ws + OFF_PM;
    unsigned* flags = (unsigned*)(ws + OFF_FLAGS);

    const int FUSED_LDS = 39800 * 4;   // 159200 B
    hipFuncSetAttribute((const void*)fused_kernel, hipFuncAttributeMaxDynamicSharedMemorySize, FUSED_LDS);

    hipMemsetAsync(flags, 0, BB*32*sizeof(unsigned), stream);

    dim3 blk(256);
    // XW = x @ W_r + b_r        (4096 x 1024, K=256)
    gemm_nn<64,64,16><<<dim3(NG4/64, (BB*LL)/64), blk, 0, stream>>>(
        x, DD, W_r, NG4, b_r, XW, NG4, BB*LL, NG4, DD);
    // F  = W_c[:256,:] @ W_w    (256 x 1024, K=256)
    gemm_nn<64,64,16><<<dim3(NG4/64, DD/64), blk, 0, stream>>>(
        W_c, DD, W_w, NG4, nullptr, Fmat, NG4, DD, NG4, DD);
    // Bm = W_c[256:,:] @ W_w    (256 x 1024, K=256)
    gemm_nn<64,64,16><<<dim3(NG4/64, DD/64), blk, 0, stream>>>(
        W_c + (size_t)DD*DD, DD, W_w, NG4, nullptr, Bmw, NG4, DD, NG4, DD);
    // b2 = b_c @ W_w + b_w
    b2_kernel<<<dim3(NG4/256), blk, 0, stream>>>(b_c, W_w, b_w, B2);
    // fused persistent reader+writer
    fused_kernel<<<dim3(BB*WGB), blk, FUSED_LDS, stream>>>(
        XW, Fmat, Bmw, B2, U_r, U_w, x, HR, HWb, PMAX, PSUM, RHO, PM, flags, (float*)d_out);
}

// Round 6
// 3946.988 us; speedup vs baseline: 11.4197x; 1.0093x over previous
//
#include <hip/hip_runtime.h>
#include <math.h>

#define BB 8
#define LL 512
#define DD 256
#define NG4 1024
#define WGB 32     // WGs per batch
#define WR 16      // mem rows per WG
#define WU 8       // units per WG
#define MLD 264    // padded leading dim for mems tile

typedef __attribute__((ext_vector_type(4))) float f32x4;
typedef __attribute__((ext_vector_type(4))) unsigned u32x4;

// ---- workspace layout (float offsets) ----
static const size_t OFF_XW    = 0;
static const size_t OFF_F     = OFF_XW + (size_t)BB*LL*NG4;     // F = Wc_top @ Ww   (256x1024)
static const size_t OFF_BMW   = OFF_F + (size_t)DD*NG4;         // Bm = Wc_bot @ Ww  (256x1024)
static const size_t OFF_B2    = OFF_BMW + (size_t)DD*NG4;       // b2 = b_c@Ww + b_w (1024)
static const size_t OFF_HR    = OFF_B2 + NG4;                   // [2][B][256] h_r double buffer
static const size_t OFF_HW    = OFF_HR + (size_t)2*BB*DD;       // [B][256]   h_w
static const size_t OFF_PMAX  = OFF_HW + (size_t)BB*DD;         // [B][32]
static const size_t OFF_PSUM  = OFF_PMAX + (size_t)BB*WGB;      // [B][32]
static const size_t OFF_RHO   = OFF_PSUM + (size_t)BB*WGB;      // [B][32] rho partial dots
static const size_t OFF_PM    = OFF_RHO + (size_t)BB*WGB;       // [B][32][256]
static const size_t OFF_FLAGS = OFF_PM + (size_t)BB*WGB*DD;     // [B][32] u32 epoch flags
static const size_t TOTAL_WS  = OFF_FLAGS + BB*WGB;             // floats

__device__ __forceinline__ float hsig(float x) {
    return fminf(fmaxf(0.2f*x + 0.5f, 0.0f), 1.0f);
}

// coherent (bypass per-XCD L2) scalar access
__device__ __forceinline__ void st_coh(float* p, float v) {
    __hip_atomic_store(p, v, __ATOMIC_RELAXED, __HIP_MEMORY_SCOPE_AGENT);
}
__device__ __forceinline__ float ld_coh(const float* p) {
    return __hip_atomic_load(p, __ATOMIC_RELAXED, __HIP_MEMORY_SCOPE_AGENT);
}
__device__ __forceinline__ void st_coh_u(unsigned* p, unsigned v) {
    __hip_atomic_store(p, v, __ATOMIC_RELAXED, __HIP_MEMORY_SCOPE_AGENT);
}

// coherent 16B flag load (4 flags at once)
__device__ __forceinline__ u32x4 ld_coh_u4(const unsigned* p) {
    u32x4 r;
    asm volatile("global_load_dwordx4 %0, %1, off sc0 sc1\n\t"
                 "s_waitcnt vmcnt(0)"
                 : "=&v"(r) : "v"(p) : "memory");
    return r;
}

// per-wave poll: lanes 0-7 of EVERY wave read the 32-flag block; wave exits
// when all flags >= target. No syncthreads — caller orders LDS use after.
__device__ __forceinline__ void wave_poll(const unsigned* flb, unsigned target, int tid) {
    if ((tid & 63) < 8) {
        const unsigned* fp = flb + (tid & 63)*4;
        for (;;) {
            u32x4 v = ld_coh_u4(fp);
            if (v[0] >= target && v[1] >= target && v[2] >= target && v[3] >= target) break;
        }
    }
}

// 8 coherent float4 loads, single drain at the end (pipelined at MALL)
__device__ __forceinline__ void ld_pm8(
    const f32x4* p0, const f32x4* p1, const f32x4* p2, const f32x4* p3,
    const f32x4* p4, const f32x4* p5, const f32x4* p6, const f32x4* p7,
    f32x4& a0, f32x4& a1, f32x4& a2, f32x4& a3,
    f32x4& a4, f32x4& a5, f32x4& a6, f32x4& a7)
{
    asm volatile(
        "global_load_dwordx4 %0, %8, off sc0 sc1\n\t"
        "global_load_dwordx4 %1, %9, off sc0 sc1\n\t"
        "global_load_dwordx4 %2, %10, off sc0 sc1\n\t"
        "global_load_dwordx4 %3, %11, off sc0 sc1\n\t"
        "global_load_dwordx4 %4, %12, off sc0 sc1\n\t"
        "global_load_dwordx4 %5, %13, off sc0 sc1\n\t"
        "global_load_dwordx4 %6, %14, off sc0 sc1\n\t"
        "global_load_dwordx4 %7, %15, off sc0 sc1\n\t"
        "s_waitcnt vmcnt(0)"
        : "=&v"(a0), "=&v"(a1), "=&v"(a2), "=&v"(a3),
          "=&v"(a4), "=&v"(a5), "=&v"(a6), "=&v"(a7)
        : "v"(p0), "v"(p1), "v"(p2), "v"(p3),
          "v"(p4), "v"(p5), "v"(p6), "v"(p7)
        : "memory");
}

// ---- simple fp32 tiled GEMM ----
template<int TM, int TN, int TK>
__global__ void __launch_bounds__(256) gemm_nn(
    const float* __restrict__ A, int lda,
    const float* __restrict__ Bmat, int ldb,
    const float* __restrict__ bias,
    float* __restrict__ C, int ldc,
    int M, int N, int K)
{
    __shared__ float As[TK][TM];
    __shared__ float Bs[TK][TN];
    const int m0 = blockIdx.y * TM, n0 = blockIdx.x * TN;
    const int tid = threadIdx.x;
    const int tx = tid % (TN/4);
    const int ty = tid / (TN/4);
    float acc[4][4] = {};
    for (int k0 = 0; k0 < K; k0 += TK) {
        {
            const int e = tid*4;
            const int m = e / TK, k = e % TK;
            const float4 v = *reinterpret_cast<const float4*>(&A[(size_t)(m0+m)*lda + k0 + k]);
            As[k+0][m] = v.x; As[k+1][m] = v.y; As[k+2][m] = v.z; As[k+3][m] = v.w;
        }
        {
            const int e = tid*4;
            const int k = e / TN, n = e % TN;
            const float4 v = *reinterpret_cast<const float4*>(&Bmat[(size_t)(k0+k)*ldb + n0 + n]);
            Bs[k][n+0] = v.x; Bs[k][n+1] = v.y; Bs[k][n+2] = v.z; Bs[k][n+3] = v.w;
        }
        __syncthreads();
        #pragma unroll
        for (int kk = 0; kk < TK; ++kk) {
            float a[4], bv[4];
            #pragma unroll
            for (int i = 0; i < 4; ++i) a[i] = As[kk][ty*4+i];
            #pragma unroll
            for (int j = 0; j < 4; ++j) bv[j] = Bs[kk][tx*4+j];
            #pragma unroll
            for (int i = 0; i < 4; ++i)
                #pragma unroll
                for (int j = 0; j < 4; ++j) acc[i][j] += a[i]*bv[j];
        }
        __syncthreads();
    }
    #pragma unroll
    for (int i = 0; i < 4; ++i) {
        const int m = m0 + ty*4 + i;
        #pragma unroll
        for (int j = 0; j < 4; ++j) {
            const int n = n0 + tx*4 + j;
            C[(size_t)m*ldc + n] = acc[i][j] + (bias ? bias[n] : 0.0f);
        }
    }
}

// b2[n] = b_w[n] + sum_k b_c[k]*W_w[k][n]
__global__ void __launch_bounds__(256) b2_kernel(
    const float* __restrict__ bc, const float* __restrict__ Ww,
    const float* __restrict__ bw, float* __restrict__ B2)
{
    const int n = blockIdx.x*256 + threadIdx.x;
    float a = bw[n];
    for (int k = 0; k < DD; ++k) a += bc[k]*Ww[(size_t)k*NG4 + n];
    B2[n] = a;
}

// ---- fused reader+writer persistent kernel ----
// Dataflow identical to validated round-5 kernel. Changes:
//  - flag-array barrier: parallel per-WG epoch stores (no RMW convoy),
//    per-wave 8-lane dwordx4 polling
//  - every wave issues its post-barrier coherent loads immediately after
//    its own detect (phase syncthreads comes after issue)
//  - XW prefetch consumed (LDS write) before barrier-1 drain so the
//    pre-flag vmcnt(0) only covers fast MALL stores
__global__ void __launch_bounds__(256) fused_kernel(
    const float* __restrict__ XW, const float* __restrict__ Fw,
    const float* __restrict__ Bm, const float* __restrict__ B2,
    const float* __restrict__ Ur, const float* __restrict__ Uw,
    const float* __restrict__ x,
    float* __restrict__ HR, float* __restrict__ HWb,
    float* __restrict__ PMAX, float* __restrict__ PSUM, float* __restrict__ RHO,
    float* __restrict__ PM,
    unsigned* __restrict__ flags, float* __restrict__ out)
{
    extern __shared__ float sm[];
    float* Urs  = sm;              // [256][32]
    float* Uws  = Urs + 8192;      // [256][32]
    float* Fs   = Uws + 8192;      // [256][32]
    float* Bms  = Fs + 8192;       // [256][32]
    float* mems = Bms + 8192;      // [16][MLD]
    float* hr2  = mems + WR*MLD;   // [2][256] h_r parity slots
    float* hw   = hr2 + 512;       // 256
    float* ms   = hw + 256;        // 256
    float* zredR= ms + 256;        // 256
    float* zredW= zredR + 256;     // 256
    float* red4 = zredW + 256;     // [4][256]
    float* xws  = red4 + 1024;     // 32
    float* b2s  = xws + 32;        // 32
    float* zrs  = b2s + 32;        // 32
    float* zws  = zrs + 32;        // 32
    float* fwS  = zws + 32;        // 32
    float* d1   = fwS + 32;        // 16
    float* zp   = d1 + 16;         // 16
    float* esx  = zp + 16;         // 16
    float* wv   = esx + 16;        // 16
    float* cr   = wv + 16;         // 8
    float* cw   = cr + 8;          // 8
    float* misc = cw + 8;          // [0]=scale, [1]=invS, [2]=beta

    const int b   = (int)blockIdx.x & 7;    // team -> same XCD (heuristic)
    const int wg  = (int)blockIdx.x >> 3;   // 0..31
    const int tid = threadIdx.x;
    const int R0  = wg*WR;
    const int U0  = wg*WU;
    const int gc32 = (tid>>3)*DD + U0 + (tid&7);   // global col for lane<32

    // --- init: weight slices ---
    for (int it = 0; it < 32; ++it) {
        const int e = it*256 + tid;
        const int k = e >> 5, cl = e & 31;
        const int gc = (cl>>3)*DD + U0 + (cl&7);
        Urs[k*32+cl] = Ur[(size_t)k*NG4 + gc];
        Uws[k*32+cl] = Uw[(size_t)k*NG4 + gc];
        Fs [k*32+cl] = Fw[(size_t)k*NG4 + gc];
        Bms[k*32+cl] = Bm[(size_t)k*NG4 + gc];
    }
    if (tid < 32) b2s[tid] = B2[gc32];
    for (int r = 0; r < WR; ++r)
        mems[r*MLD + tid] = x[((size_t)b*LL + R0 + r)*DD + tid];
    // prologue: full h_r[0] computed locally (h=0 -> z = XW row 0)
    {
        const size_t base = (size_t)b*LL*NG4;
        const float zi = XW[base + tid];
        const float zg = XW[base + 512 + tid];
        const float zo = XW[base + 768 + tid];
        const float c0 = hsig(zi)*tanhf(zg);
        hr2[tid] = hsig(zo)*tanhf(c0);
        hr2[256 + tid] = 0.f;
        if (tid >= U0 && tid < U0+WU) cr[tid-U0] = c0;
    }
    if (tid < 16) { zp[tid] = 0.f; d1[tid] = 0.f; esx[tid] = 0.f; }
    if (tid < 8)  cw[tid] = 0.f;
    if (tid < 4)  misc[tid] = 0.f;
    __syncthreads();

    unsigned* flb = &flags[b*WGB];

    for (int s = 0; s <= LL; ++s) {
        const bool doW = (s >= 1);
        float* hrN_s = hr2 + (s&1)*256;        // h_r[s]
        float* hrO_s = hr2 + ((s+1)&1)*256;    // h_r[s-1] = o_tau

        // ================= PHASE A (writer tau = s-1 partials) =================
        // loads issued per-wave (barrier-2 of prev step already verified per-wave)
        float xw_r = 0.f;
        if (s <= LL-2 && tid < 32) xw_r = XW[((size_t)b*LL + s + 1)*NG4 + gc32];
        float hw_r = 0.f, rho_r = 0.f;
        if (s >= 2) {
            hw_r = ld_coh(&HWb[b*DD + tid]);                 // h_w(s-2)
            if (tid < 32) rho_r = ld_coh(&RHO[b*WGB + tid]); // slice dots o_{s-1}.h_w(s-2)
        }
        hw[tid] = hw_r;
        __syncthreads();   // SYNC_A0: hw visible; d1/zp (prev-step LDS) safe to read

        // consume XW prefetch now so barrier-1 drain excludes the HBM load
        if (s <= LL-2 && tid < 32) xws[tid] = xw_r;

        // d2 from rho partials + local softmax (wave 0 only)
        if (tid < 32) {
            float d2 = rho_r;
            #pragma unroll
            for (int off = 16; off; off >>= 1) d2 += __shfl_xor(d2, off, 32);
            if (doW && tid < 16) {
                const float zpv = zp[tid];
                const float sc  = (1.f - zpv)*d1[tid] + zpv*d2;
                float m = sc;
                #pragma unroll
                for (int off = 8; off; off >>= 1) m = fmaxf(m, __shfl_xor(m, off, 16));
                const float e = __expf(sc - m);
                esx[tid] = e;
                wv[tid]  = e*(1.f - zpv);
                float sum = e, bp = e*zpv;
                #pragma unroll
                for (int off = 8; off; off >>= 1) {
                    sum += __shfl_xor(sum, off, 16);
                    bp  += __shfl_xor(bp,  off, 16);
                }
                if (tid == 0) {
                    misc[2] = bp;
                    st_coh(&PMAX[b*WGB + wg], m);
                    st_coh(&PSUM[b*WGB + wg], sum);
                }
            }
        }
        __syncthreads();   // SYNC_A1: wv, misc[2] visible

        if (doW) {   // pm partial over mem_{s-2} (mems holds mem_{s-3})
            float p = misc[2]*hw_r;
            #pragma unroll
            for (int r = 0; r < WR; ++r) p += wv[r]*mems[r*MLD + tid];
            st_coh(&PM[((size_t)b*WGB + wg)*DD + tid], p);
        }

        // --- barrier 1: drain, publish flag, hidden work, per-wave poll ---
        asm volatile("s_waitcnt vmcnt(0)" ::: "memory");
        __syncthreads();   // SYNC_A2: all waves drained
        const unsigned tgt1 = 2u*(unsigned)s + 1u;
        if (tid == 0) st_coh_u(&flb[wg], tgt1);
        if (s >= 2) {    // mem_{s-3} -> mem_{s-2} (hidden; column-exclusive per thread)
            #pragma unroll
            for (int r = 0; r < WR; ++r) {
                const float z = zp[r];
                float* mp = &mems[r*MLD + tid];
                *mp = *mp*(1.f - z) + hw_r*z;
            }
        }
        if (doW) {       // hw@Uw + o@F GEMV partial (hidden)
            const int kc = tid >> 5, cl = tid & 31, k0 = kc*32;
            float a = 0.f;
            #pragma unroll 8
            for (int k = k0; k < k0+32; ++k)
                a += hw[k]*Uws[k*32+cl] + hrO_s[k]*Fs[k*32+cl];
            zredW[tid] = a;
        }
        wave_poll(flb, tgt1, tid);

        // ================= PHASE B =================
        // per-wave post-detect loads (registers only; no LDS dependency)
        float hrN_r = 0.f;
        if (s >= 1 && s <= LL-1) hrN_r = ld_coh(&HR[((size_t)(s&1))*BB*DD + b*DD + tid]);
        float pmx_r = 0.f, ps_r = 0.f;
        if (doW && tid < 32) {
            pmx_r = ld_coh(&PMAX[b*WGB + tid]);
            ps_r  = ld_coh(&PSUM[b*WGB + tid]);
        }
        f32x4 a0,a1,a2,a3,a4,a5,a6,a7;
        const int w0 = tid >> 6, dq = tid & 63;
        if (doW) {
            const float* pmb = PM + (size_t)b*WGB*DD;
            ld_pm8((const f32x4*)(pmb + (w0+ 0)*DD) + dq, (const f32x4*)(pmb + (w0+ 4)*DD) + dq,
                   (const f32x4*)(pmb + (w0+ 8)*DD) + dq, (const f32x4*)(pmb + (w0+12)*DD) + dq,
                   (const f32x4*)(pmb + (w0+16)*DD) + dq, (const f32x4*)(pmb + (w0+20)*DD) + dq,
                   (const f32x4*)(pmb + (w0+24)*DD) + dq, (const f32x4*)(pmb + (w0+28)*DD) + dq,
                   a0,a1,a2,a3,a4,a5,a6,a7);
        }
        if (s >= 1 && s <= LL-1) hrN_s[tid] = hrN_r;
        if (doW && tid < 32) {   // global softmax weights (regs + own-lane data only)
            float g = pmx_r;
            #pragma unroll
            for (int off = 16; off; off >>= 1) g = fmaxf(g, __shfl_xor(g, off, 32));
            const float fw = __expf(pmx_r - g);
            float S = ps_r*fw;
            #pragma unroll
            for (int off = 16; off; off >>= 1) S += __shfl_xor(S, off, 32);
            fwS[tid] = fw;
            if (tid == 0)  misc[1] = 1.f/S;
            if (tid == wg) misc[0] = fw/S;
        }
        __syncthreads();   // SYNC_B1: hrN, fwS, misc visible

        if (s <= LL-2) {   // reader GEMV partial
            const int kc = tid >> 5, cl = tid & 31, k0 = kc*32;
            float a = 0.f;
            #pragma unroll 8
            for (int k = k0; k < k0+32; ++k) a += hrN_s[k]*Urs[k*32+cl];
            zredR[tid] = a;
        }
        if (doW) {
            // m_rt combine
            f32x4 acc = a0*fwS[w0];
            acc += a1*fwS[w0+4];  acc += a2*fwS[w0+8];
            acc += a3*fwS[w0+12]; acc += a4*fwS[w0+16];
            acc += a5*fwS[w0+20]; acc += a6*fwS[w0+24];
            acc += a7*fwS[w0+28];
            *(f32x4*)(red4 + w0*DD + dq*4) = acc;
        }
        __syncthreads();   // SYNC_B2: red4, zredR visible
        if (doW) {
            ms[tid] = (red4[tid] + red4[DD+tid] + red4[2*DD+tid] + red4[3*DD+tid]) * misc[1];
            if (tid < 16) zp[tid] = esx[tid]*misc[0];   // z_{s-1} for next step
        }
        __syncthreads();   // SYNC_B3: ms visible
        if (doW) {         // += ms@Bm  (zredW already holds hw@Uw + o@F)
            const int kc = tid >> 5, cl = tid & 31, k0 = kc*32;
            float a = zredW[tid];
            #pragma unroll 8
            for (int k = k0; k < k0+32; ++k) a += ms[k]*Bms[k*32+cl];
            zredW[tid] = a;
        }
        __syncthreads();   // SYNC_B4
        if (tid < 32) {
            if (doW) {
                float z = b2s[tid];
                #pragma unroll
                for (int q = 0; q < 8; ++q) z += zredW[q*32 + tid];
                zws[tid] = z;
            }
            if (s <= LL-2) {
                float z = xws[tid];
                #pragma unroll
                for (int q = 0; q < 8; ++q) z += zredR[q*32 + tid];
                zrs[tid] = z;
            }
        }
        __syncthreads();   // SYNC_B5: zws, zrs visible

        if (doW && tid < 8) {   // writer gates + h_w slice + rho partial
            const float ig = hsig(zws[tid]);
            const float fg = hsig(zws[8+tid]);
            const float gg = tanhf(zws[16+tid]);
            const float og = hsig(zws[24+tid]);
            const float c  = fg*cw[tid] + ig*gg;
            cw[tid] = c;
            const float h = og*tanhf(c);
            st_coh(&HWb[b*DD + U0 + tid], h);
            if (s < LL) {
                float rr = h * hrN_s[U0 + tid];    // o_s . h_w(s-1), own slice
                rr += __shfl_down(rr, 4, 8);
                rr += __shfl_down(rr, 2, 8);
                rr += __shfl_down(rr, 1, 8);
                if (tid == 0) st_coh(&RHO[b*WGB + wg], rr);
            }
            if (s == LL) out[b*DD + U0 + tid] = h;
        }
        if (s <= LL-2 && tid < 8) {   // reader gates + h_r[s+1] slice
            const float ig = hsig(zrs[tid]);
            const float fg = hsig(zrs[8+tid]);
            const float gg = tanhf(zrs[16+tid]);
            const float og = hsig(zrs[24+tid]);
            const float c  = fg*cr[tid] + ig*gg;
            cr[tid] = c;
            st_coh(&HR[((size_t)((s+1)&1))*BB*DD + b*DD + U0 + tid], og*tanhf(c));
        }

        // --- barrier 2: drain, publish flag, hidden d1', per-wave poll ---
        if (s < LL) {
            asm volatile("s_waitcnt vmcnt(0)" ::: "memory");
            __syncthreads();   // SYNC_B6: all waves drained
            const unsigned tgt2 = 2u*(unsigned)s + 2u;
            if (tid == 0) st_coh_u(&flb[wg], tgt2);
            {   // d1' = h_r[s] . mem rows (hidden)
                const int r = tid >> 4, j = tid & 15;
                float a = 0.f;
                const float* mrow = mems + r*MLD;
                #pragma unroll 4
                for (int d = j; d < DD; d += 16) a += hrN_s[d]*mrow[d];
                #pragma unroll
                for (int off = 8; off; off >>= 1) a += __shfl_down(a, off, 16);
                if (j == 0) d1[r] = a;
            }
            wave_poll(flb, tgt2, tid);
        }
    }
}

extern "C" void kernel_launch(void* const* d_in, const int* in_sizes, int n_in,
                              void* d_out, int out_size, void* d_ws, size_t ws_size,
                              hipStream_t stream) {
    const float* x   = (const float*)d_in[0];
    const float* W_r = (const float*)d_in[1];
    const float* U_r = (const float*)d_in[2];
    const float* b_r = (const float*)d_in[3];
    const float* W_w = (const float*)d_in[4];
    const float* U_w = (const float*)d_in[5];
    const float* b_w = (const float*)d_in[6];
    const float* W_c = (const float*)d_in[7];
    const float* b_c = (const float*)d_in[8];
    (void)in_sizes; (void)n_in;

    if (ws_size < TOTAL_WS * sizeof(float)) return;

    float* ws   = (float*)d_ws;
    float* XW   = ws + OFF_XW;
    float* Fmat = ws + OFF_F;
    float* Bmw  = ws + OFF_BMW;
    float* B2   = ws + OFF_B2;
    float* HR   = ws + OFF_HR;
    float* HWb  = ws + OFF_HW;
    float* PMAX = ws + OFF_PMAX;
    float* PSUM = ws + OFF_PSUM;
    float* RHO  = ws + OFF_RHO;
    float* PM   = ws + OFF_PM;
    unsigned* flags = (unsigned*)(ws + OFF_FLAGS);

    const int FUSED_LDS = 39800 * 4;   // 159200 B
    hipFuncSetAttribute((const void*)fused_kernel, hipFuncAttributeMaxDynamicSharedMemorySize, FUSED_LDS);

    hipMemsetAsync(flags, 0, BB*WGB*sizeof(unsigned), stream);

    dim3 blk(256);
    // XW = x @ W_r + b_r        (4096 x 1024, K=256)
    gemm_nn<64,64,16><<<dim3(NG4/64, (BB*LL)/64), blk, 0, stream>>>(
        x, DD, W_r, NG4, b_r, XW, NG4, BB*LL, NG4, DD);
    // F  = W_c[:256,:] @ W_w    (256 x 1024, K=256)
    gemm_nn<64,64,16><<<dim3(NG4/64, DD/64), blk, 0, stream>>>(
        W_c, DD, W_w, NG4, nullptr, Fmat, NG4, DD, NG4, DD);
    // Bm = W_c[256:,:] @ W_w    (256 x 1024, K=256)
    gemm_nn<64,64,16><<<dim3(NG4/64, DD/64), blk, 0, stream>>>(
        W_c + (size_t)DD*DD, DD, W_w, NG4, nullptr, Bmw, NG4, DD, NG4, DD);
    // b2 = b_c @ W_w + b_w
    b2_kernel<<<dim3(NG4/256), blk, 0, stream>>>(b_c, W_w, b_w, B2);
    // fused persistent reader+writer
    fused_kernel<<<dim3(BB*WGB), blk, FUSED_LDS, stream>>>(
        XW, Fmat, Bmw, B2, U_r, U_w, x, HR, HWb, PMAX, PSUM, RHO, PM, flags, (float*)d_out);
}

// Round 8
// 3783.522 us; speedup vs baseline: 11.9131x; 1.0432x over previous
//
#include <hip/hip_runtime.h>
#include <math.h>

#define BB 8
#define LL 512
#define DD 256
#define NG4 1024
#define WGB 32     // WGs per batch
#define WR 16      // mem rows per WG
#define WU 8      // units per WG
#define MLD 264    // padded leading dim for mems tile

typedef __attribute__((ext_vector_type(4))) float f32x4;
typedef __attribute__((ext_vector_type(2))) unsigned u32x2;
typedef __attribute__((ext_vector_type(4))) unsigned u32x4;

// ---- workspace layout (float offsets) ----
static const size_t OFF_XW    = 0;
static const size_t OFF_F     = OFF_XW + (size_t)BB*LL*NG4;     // F = Wc_top @ Ww   (256x1024)
static const size_t OFF_BMW   = OFF_F + (size_t)DD*NG4;         // Bm = Wc_bot @ Ww  (256x1024)
static const size_t OFF_B2    = OFF_BMW + (size_t)DD*NG4;       // b2 = b_c@Ww + b_w (1024)
static const size_t OFF_HRT   = OFF_B2 + NG4;                   // [2][B][256] {val,tag} pairs
static const size_t OFF_HWT   = OFF_HRT + (size_t)2*BB*DD*2;    // [B][256] pairs
static const size_t OFF_RHOT  = OFF_HWT + (size_t)BB*DD*2;      // [B][32] pairs
static const size_t OFF_CHUNK = OFF_RHOT + (size_t)BB*WGB*2;    // [B][32] {pmax,psum,tag,0}
static const size_t OFF_PM    = OFF_CHUNK + (size_t)BB*WGB*4;   // [B][32][256] plain
static const size_t TOTAL_WS  = OFF_PM + (size_t)BB*WGB*DD;     // floats

__device__ __forceinline__ float hsig(float x) {
    return fminf(fmaxf(0.2f*x + 0.5f, 0.0f), 1.0f);
}

// coherent (MALL, sc0 sc1) primitives — the validated cross-XCD path
__device__ __forceinline__ void st_coh(float* p, float v) {
    __hip_atomic_store(p, v, __ATOMIC_RELAXED, __HIP_MEMORY_SCOPE_AGENT);
}
// tagged 8B pair: {f32 value, u32 epoch} in ONE instruction
__device__ __forceinline__ void st_pair(unsigned* p, float v, unsigned tag) {
    u32x2 d; d[0] = __float_as_uint(v); d[1] = tag;
    asm volatile("global_store_dwordx2 %0, %1, off sc0 sc1" :: "v"(p), "v"(d) : "memory");
}
__device__ __forceinline__ u32x2 ld_pair(const unsigned* p) {
    u32x2 r;
    asm volatile("global_load_dwordx2 %0, %1, off sc0 sc1\n\ts_waitcnt vmcnt(0)"
                 : "=&v"(r) : "v"(p) : "memory");
    return r;
}
__device__ __forceinline__ float poll_pair(const unsigned* p, unsigned tag) {
    for (;;) {
        u32x2 r = ld_pair(p);
        if (r[1] >= tag) return __uint_as_float(r[0]);
    }
}
__device__ __forceinline__ u32x4 ld_chunk(const unsigned* p) {
    u32x4 r;
    asm volatile("global_load_dwordx4 %0, %1, off sc0 sc1\n\ts_waitcnt vmcnt(0)"
                 : "=&v"(r) : "v"(p) : "memory");
    return r;
}
// 8 coherent float4 loads, single drain (pipelined at MALL)
__device__ __forceinline__ void ld_pm8(
    const f32x4* p0, const f32x4* p1, const f32x4* p2, const f32x4* p3,
    const f32x4* p4, const f32x4* p5, const f32x4* p6, const f32x4* p7,
    f32x4& a0, f32x4& a1, f32x4& a2, f32x4& a3,
    f32x4& a4, f32x4& a5, f32x4& a6, f32x4& a7)
{
    asm volatile(
        "global_load_dwordx4 %0, %8, off sc0 sc1\n\t"
        "global_load_dwordx4 %1, %9, off sc0 sc1\n\t"
        "global_load_dwordx4 %2, %10, off sc0 sc1\n\t"
        "global_load_dwordx4 %3, %11, off sc0 sc1\n\t"
        "global_load_dwordx4 %4, %12, off sc0 sc1\n\t"
        "global_load_dwordx4 %5, %13, off sc0 sc1\n\t"
        "global_load_dwordx4 %6, %14, off sc0 sc1\n\t"
        "global_load_dwordx4 %7, %15, off sc0 sc1\n\t"
        "s_waitcnt vmcnt(0)"
        : "=&v"(a0), "=&v"(a1), "=&v"(a2), "=&v"(a3),
          "=&v"(a4), "=&v"(a5), "=&v"(a6), "=&v"(a7)
        : "v"(p0), "v"(p1), "v"(p2), "v"(p3),
          "v"(p4), "v"(p5), "v"(p6), "v"(p7)
        : "memory");
}

// ---- simple fp32 tiled GEMM ----
template<int TM, int TN, int TK>
__global__ void __launch_bounds__(256) gemm_nn(
    const float* __restrict__ A, int lda,
    const float* __restrict__ Bmat, int ldb,
    const float* __restrict__ bias,
    float* __restrict__ C, int ldc,
    int M, int N, int K)
{
    __shared__ float As[TK][TM];
    __shared__ float Bs[TK][TN];
    const int m0 = blockIdx.y * TM, n0 = blockIdx.x * TN;
    const int tid = threadIdx.x;
    const int tx = tid % (TN/4);
    const int ty = tid / (TN/4);
    float acc[4][4] = {};
    for (int k0 = 0; k0 < K; k0 += TK) {
        {
            const int e = tid*4;
            const int m = e / TK, k = e % TK;
            const float4 v = *reinterpret_cast<const float4*>(&A[(size_t)(m0+m)*lda + k0 + k]);
            As[k+0][m] = v.x; As[k+1][m] = v.y; As[k+2][m] = v.z; As[k+3][m] = v.w;
        }
        {
            const int e = tid*4;
            const int k = e / TN, n = e % TN;
            const float4 v = *reinterpret_cast<const float4*>(&Bmat[(size_t)(k0+k)*ldb + n0 + n]);
            Bs[k][n+0] = v.x; Bs[k][n+1] = v.y; Bs[k][n+2] = v.z; Bs[k][n+3] = v.w;
        }
        __syncthreads();
        #pragma unroll
        for (int kk = 0; kk < TK; ++kk) {
            float a[4], bv[4];
            #pragma unroll
            for (int i = 0; i < 4; ++i) a[i] = As[kk][ty*4+i];
            #pragma unroll
            for (int j = 0; j < 4; ++j) bv[j] = Bs[kk][tx*4+j];
            #pragma unroll
            for (int i = 0; i < 4; ++i)
                #pragma unroll
                for (int j = 0; j < 4; ++j) acc[i][j] += a[i]*bv[j];
        }
        __syncthreads();
    }
    #pragma unroll
    for (int i = 0; i < 4; ++i) {
        const int m = m0 + ty*4 + i;
        #pragma unroll
        for (int j = 0; j < 4; ++j) {
            const int n = n0 + tx*4 + j;
            C[(size_t)m*ldc + n] = acc[i][j] + (bias ? bias[n] : 0.0f);
        }
    }
}

// b2[n] = b_w[n] + sum_k b_c[k]*W_w[k][n]
__global__ void __launch_bounds__(256) b2_kernel(
    const float* __restrict__ bc, const float* __restrict__ Ww,
    const float* __restrict__ bw, float* __restrict__ B2)
{
    const int n = blockIdx.x*256 + threadIdx.x;
    float a = bw[n];
    for (int k = 0; k < DD; ++k) a += bc[k]*Ww[(size_t)k*NG4 + n];
    B2[n] = a;
}

// ---- fused reader+writer persistent kernel, barrier-free ----
// Dataflow identical to validated rounds 5/6. All cross-WG data is
// self-synchronizing {value, epoch} pairs (consumers poll their own words);
// PM keeps drain-then-tag via the pmax/psum CHUNK. Both explicit barriers
// removed. Flow control (no overwrite before consumption) is causal:
// a WG reaches the overwrite point only after polling epoch-s data from all
// peers, which each peer publishes only after its own epoch-s consumption.
__global__ void __launch_bounds__(256) fused_kernel(
    const float* __restrict__ XW, const float* __restrict__ Fw,
    const float* __restrict__ Bm, const float* __restrict__ B2,
    const float* __restrict__ Ur, const float* __restrict__ Uw,
    const float* __restrict__ x,
    unsigned* __restrict__ HRT, unsigned* __restrict__ HWT,
    unsigned* __restrict__ RHOT, unsigned* __restrict__ CHUNK,
    float* __restrict__ PM, float* __restrict__ out)
{
    extern __shared__ float sm[];
    float* Urs  = sm;              // [256][32]
    float* Uws  = Urs + 8192;      // [256][32]
    float* Fs   = Uws + 8192;      // [256][32]
    float* Bms  = Fs + 8192;       // [256][32]
    float* mems = Bms + 8192;      // [16][MLD]
    float* hr2  = mems + WR*MLD;   // [2][256] h_r parity slots
    float* hw   = hr2 + 512;       // 256
    float* ms   = hw + 256;        // 256
    float* zredR= ms + 256;        // 256
    float* zredW= zredR + 256;     // 256
    float* red4 = zredW + 256;     // [4][256]
    float* xws  = red4 + 1024;     // 32
    float* b2s  = xws + 32;        // 32
    float* zrs  = b2s + 32;        // 32
    float* zws  = zrs + 32;        // 32
    float* fwS  = zws + 32;        // 32
    float* d1   = fwS + 32;        // 16
    float* zp   = d1 + 16;         // 16
    float* esx  = zp + 16;         // 16
    float* wv   = esx + 16;        // 16
    float* cr   = wv + 16;         // 8
    float* cw   = cr + 8;          // 8
    float* misc = cw + 8;          // [0]=scale, [1]=invS, [2]=beta

    const int b   = (int)blockIdx.x & 7;
    const int wg  = (int)blockIdx.x >> 3;   // 0..31
    const int tid = threadIdx.x;
    const int R0  = wg*WR;
    const int U0  = wg*WU;
    const int gc32 = (tid>>3)*DD + U0 + (tid&7);   // global col for lane<32

    // --- init: weight slices ---
    for (int it = 0; it < 32; ++it) {
        const int e = it*256 + tid;
        const int k = e >> 5, cl = e & 31;
        const int gc = (cl>>3)*DD + U0 + (cl&7);
        Urs[k*32+cl] = Ur[(size_t)k*NG4 + gc];
        Uws[k*32+cl] = Uw[(size_t)k*NG4 + gc];
        Fs [k*32+cl] = Fw[(size_t)k*NG4 + gc];
        Bms[k*32+cl] = Bm[(size_t)k*NG4 + gc];
    }
    if (tid < 32) b2s[tid] = B2[gc32];
    for (int r = 0; r < WR; ++r)
        mems[r*MLD + tid] = x[((size_t)b*LL + R0 + r)*DD + tid];
    // prologue: full h_r[0] computed locally (h=0 -> z = XW row 0)
    {
        const size_t base = (size_t)b*LL*NG4;
        const float zi = XW[base + tid];
        const float zg = XW[base + 512 + tid];
        const float zo = XW[base + 768 + tid];
        const float c0 = hsig(zi)*tanhf(zg);
        hr2[tid] = hsig(zo)*tanhf(c0);
        hr2[256 + tid] = 0.f;
        if (tid >= U0 && tid < U0+WU) cr[tid-U0] = c0;
    }
    if (tid < 16) { zp[tid] = 0.f; d1[tid] = 0.f; esx[tid] = 0.f; }
    if (tid < 8)  cw[tid] = 0.f;
    if (tid < 4)  misc[tid] = 0.f;
    __syncthreads();

    for (int s = 0; s <= LL; ++s) {
        const bool doW = (s >= 1);
        float* hrN_s = hr2 + (s&1)*256;        // h_r[s]
        float* hrO_s = hr2 + ((s+1)&1)*256;    // h_r[s-1] = o_tau

        // ================= PHASE A (writer tau = s-1 partials) =================
        if (s <= LL-2 && tid < 32)
            xws[tid] = XW[((size_t)b*LL + s + 1)*NG4 + gc32];   // wave0-local prefetch

        float hw_r = 0.f, rho_r = 0.f;
        if (s >= 2) {
            hw_r = poll_pair(HWT + 2*((size_t)b*DD + tid), (unsigned)(s-1));   // h_w(s-2)
            if (tid < 32)
                rho_r = poll_pair(RHOT + 2*(b*WGB + tid), (unsigned)(s-1));    // o_{s-1}.h_w(s-2) slices
        }
        hw[tid] = hw_r;
        __syncthreads();   // SYNC_A0: hw visible; prev-step LDS (d1,zp,esx) stable

        // d2 from rho partials + local softmax (wave 0 only)
        float ck_m = 0.f, ck_s = 0.f;
        if (tid < 32) {
            float d2 = rho_r;
            #pragma unroll
            for (int off = 16; off; off >>= 1) d2 += __shfl_xor(d2, off, 32);
            if (doW && tid < 16) {
                const float zpv = zp[tid];
                const float sc  = (1.f - zpv)*d1[tid] + zpv*d2;
                float m = sc;
                #pragma unroll
                for (int off = 8; off; off >>= 1) m = fmaxf(m, __shfl_xor(m, off, 16));
                const float e = __expf(sc - m);
                esx[tid] = e;
                wv[tid]  = e*(1.f - zpv);
                float sum = e, bp = e*zpv;
                #pragma unroll
                for (int off = 8; off; off >>= 1) {
                    sum += __shfl_xor(sum, off, 16);
                    bp  += __shfl_xor(bp,  off, 16);
                }
                if (tid == 0) { misc[2] = bp; ck_m = m; ck_s = sum; }
            }
        }
        __syncthreads();   // SYNC_A1: wv, misc[2] visible

        if (doW) {   // pm partial over mem_{s-2} (mems holds mem_{s-3})
            float p = misc[2]*hw_r;
            #pragma unroll
            for (int r = 0; r < WR; ++r) p += wv[r]*mems[r*MLD + tid];
            st_coh(&PM[((size_t)b*WGB + wg)*DD + tid], p);
        }
        // drain pm stores, then publish tagged chunk {pmax, psum, epoch}
        asm volatile("s_waitcnt vmcnt(0)" ::: "memory");
        __syncthreads();   // SYNC_A2: whole WG's pm acked at MALL
        if (doW && tid == 0) {
            u32x4 d; d[0] = __float_as_uint(ck_m); d[1] = __float_as_uint(ck_s);
            d[2] = (unsigned)s; d[3] = 0u;
            unsigned* cp = CHUNK + 4*(b*WGB + wg);
            asm volatile("global_store_dwordx4 %0, %1, off sc0 sc1" :: "v"(cp), "v"(d) : "memory");
        }
        if (s >= 2) {    // mem_{s-3} -> mem_{s-2}
            #pragma unroll
            for (int r = 0; r < WR; ++r) {
                const float z = zp[r];
                float* mp = &mems[r*MLD + tid];
                *mp = *mp*(1.f - z) + hw_r*z;
            }
        }
        if (doW) {       // hw@Uw + o@F GEMV partial
            const int kc = tid >> 5, cl = tid & 31, k0 = kc*32;
            float a = 0.f;
            #pragma unroll 8
            for (int k = k0; k < k0+32; ++k)
                a += hw[k]*Uws[k*32+cl] + hrO_s[k]*Fs[k*32+cl];
            zredW[tid] = a;
        }

        // ================= PHASE B =================
        float hrN_r = 0.f;
        if (s >= 1 && s <= LL-1)
            hrN_r = poll_pair(HRT + 2*(((size_t)(s&1)*BB + b)*DD + tid), (unsigned)s);
        float pmx_r = 0.f, ps_r = 0.f;
        if (doW && tid < 32) {
            const unsigned* cp = CHUNK + 4*(b*WGB + tid);
            u32x4 ck;
            do { ck = ld_chunk(cp); } while (ck[2] < (unsigned)s);
            pmx_r = __uint_as_float(ck[0]); ps_r = __uint_as_float(ck[1]);
        }
        if (s >= 1 && s <= LL-1) hrN_s[tid] = hrN_r;
        __syncthreads();   // SYNC_B1: hrN visible; wave0 confirmed all chunks@s

        f32x4 a0={},a1={},a2={},a3={},a4={},a5={},a6={},a7={};
        const int w0 = tid >> 6, dq = tid & 63;
        if (doW) {
            const float* pmb = PM + (size_t)b*WGB*DD;
            ld_pm8((const f32x4*)(pmb + (w0+ 0)*DD) + dq, (const f32x4*)(pmb + (w0+ 4)*DD) + dq,
                   (const f32x4*)(pmb + (w0+ 8)*DD) + dq, (const f32x4*)(pmb + (w0+12)*DD) + dq,
                   (const f32x4*)(pmb + (w0+16)*DD) + dq, (const f32x4*)(pmb + (w0+20)*DD) + dq,
                   (const f32x4*)(pmb + (w0+24)*DD) + dq, (const f32x4*)(pmb + (w0+28)*DD) + dq,
                   a0,a1,a2,a3,a4,a5,a6,a7);
        }
        if (doW && tid < 32) {   // global softmax weights
            float g = pmx_r;
            #pragma unroll
            for (int off = 16; off; off >>= 1) g = fmaxf(g, __shfl_xor(g, off, 32));
            const float fw = __expf(pmx_r - g);
            float S = ps_r*fw;
            #pragma unroll
            for (int off = 16; off; off >>= 1) S += __shfl_xor(S, off, 32);
            fwS[tid] = fw;
            if (tid == 0)  misc[1] = 1.f/S;
            if (tid == wg) misc[0] = fw/S;
        }
        if (s <= LL-2) {   // reader GEMV partial
            const int kc = tid >> 5, cl = tid & 31, k0 = kc*32;
            float a = 0.f;
            #pragma unroll 8
            for (int k = k0; k < k0+32; ++k) a += hrN_s[k]*Urs[k*32+cl];
            zredR[tid] = a;
        }
        __syncthreads();   // SYNC_B2: fwS, misc, zredR visible

        if (doW) {
            f32x4 acc = a0*fwS[w0];
            acc += a1*fwS[w0+4];  acc += a2*fwS[w0+8];
            acc += a3*fwS[w0+12]; acc += a4*fwS[w0+16];
            acc += a5*fwS[w0+20]; acc += a6*fwS[w0+24];
            acc += a7*fwS[w0+28];
            *(f32x4*)(red4 + w0*DD + dq*4) = acc;
        }
        __syncthreads();   // SYNC_B3: red4 visible
        if (doW) {
            ms[tid] = (red4[tid] + red4[DD+tid] + red4[2*DD+tid] + red4[3*DD+tid]) * misc[1];
            if (tid < 16) zp[tid] = esx[tid]*misc[0];   // z_{s-1} for next step
        }
        __syncthreads();   // SYNC_B4: ms visible
        if (doW) {         // += ms@Bm  (zredW already holds hw@Uw + o@F)
            const int kc = tid >> 5, cl = tid & 31, k0 = kc*32;
            float a = zredW[tid];
            #pragma unroll 8
            for (int k = k0; k < k0+32; ++k) a += ms[k]*Bms[k*32+cl];
            zredW[tid] = a;
        }
        __syncthreads();   // SYNC_B5
        if (tid < 32) {
            if (doW) {
                float z = b2s[tid];
                #pragma unroll
                for (int q = 0; q < 8; ++q) z += zredW[q*32 + tid];
                zws[tid] = z;
            }
            if (s <= LL-2) {
                float z = xws[tid];
                #pragma unroll
                for (int q = 0; q < 8; ++q) z += zredR[q*32 + tid];
                zrs[tid] = z;
            }
        }
        __syncthreads();   // SYNC_B6: zws, zrs visible

        if (doW && tid < 8) {   // writer gates: publish tagged h_w slice + rho
            const float ig = hsig(zws[tid]);
            const float fg = hsig(zws[8+tid]);
            const float gg = tanhf(zws[16+tid]);
            const float og = hsig(zws[24+tid]);
            const float c  = fg*cw[tid] + ig*gg;
            cw[tid] = c;
            const float h = og*tanhf(c);
            st_pair(HWT + 2*((size_t)b*DD + U0 + tid), h, (unsigned)s);
            if (s < LL) {
                float rr = h * hrN_s[U0 + tid];    // o_s . h_w(s-1), own slice
                rr += __shfl_down(rr, 4, 8);
                rr += __shfl_down(rr, 2, 8);
                rr += __shfl_down(rr, 1, 8);
                if (tid == 0) st_pair(RHOT + 2*(b*WGB + wg), rr, (unsigned)s);
            }
            if (s == LL) out[b*DD + U0 + tid] = h;
        }
        if (s <= LL-2 && tid < 8) {   // reader gates: publish tagged h_r[s+1] slice
            const float ig = hsig(zrs[tid]);
            const float fg = hsig(zrs[8+tid]);
            const float gg = tanhf(zrs[16+tid]);
            const float og = hsig(zrs[24+tid]);
            const float c  = fg*cr[tid] + ig*gg;
            cr[tid] = c;
            st_pair(HRT + 2*(((size_t)((s+1)&1)*BB + b)*DD + U0 + tid),
                    og*tanhf(c), (unsigned)(s+1));
        }
        // d1' = h_r[s] . mem_{s-2} rows (WG-local, for next step's scores)
        if (s < LL) {
            const int r = tid >> 4, j = tid & 15;
            float a = 0.f;
            const float* mrow = mems + r*MLD;
            #pragma unroll 4
            for (int d = j; d < DD; d += 16) a += hrN_s[d]*mrow[d];
            #pragma unroll
            for (int off = 8; off; off >>= 1) a += __shfl_down(a, off, 16);
            if (j == 0) d1[r] = a;
        }
        // no trailing barrier — next step's polls self-synchronize
    }
}

extern "C" void kernel_launch(void* const* d_in, const int* in_sizes, int n_in,
                              void* d_out, int out_size, void* d_ws, size_t ws_size,
                              hipStream_t stream) {
    const float* x   = (const float*)d_in[0];
    const float* W_r = (const float*)d_in[1];
    const float* U_r = (const float*)d_in[2];
    const float* b_r = (const float*)d_in[3];
    const float* W_w = (const float*)d_in[4];
    const float* U_w = (const float*)d_in[5];
    const float* b_w = (const float*)d_in[6];
    const float* W_c = (const float*)d_in[7];
    const float* b_c = (const float*)d_in[8];
    (void)in_sizes; (void)n_in;

    if (ws_size < TOTAL_WS * sizeof(float)) return;

    float* ws   = (float*)d_ws;
    float* XW   = ws + OFF_XW;
    float* Fmat = ws + OFF_F;
    float* Bmw  = ws + OFF_BMW;
    float* B2   = ws + OFF_B2;
    unsigned* HRT   = (unsigned*)(ws + OFF_HRT);
    unsigned* HWT   = (unsigned*)(ws + OFF_HWT);
    unsigned* RHOT  = (unsigned*)(ws + OFF_RHOT);
    unsigned* CHUNK = (unsigned*)(ws + OFF_CHUNK);
    float* PM   = ws + OFF_PM;

    const int FUSED_LDS = 39800 * 4;   // 159200 B
    hipFuncSetAttribute((const void*)fused_kernel, hipFuncAttributeMaxDynamicSharedMemorySize, FUSED_LDS);

    // zero all tag-carrying buffers (HRT..CHUNK contiguous)
    hipMemsetAsync(HRT, 0, (OFF_PM - OFF_HRT)*sizeof(float), stream);

    dim3 blk(256);
    // XW = x @ W_r + b_r        (4096 x 1024, K=256)
    gemm_nn<64,64,16><<<dim3(NG4/64, (BB*LL)/64), blk, 0, stream>>>(
        x, DD, W_r, NG4, b_r, XW, NG4, BB*LL, NG4, DD);
    // F  = W_c[:256,:] @ W_w    (256 x 1024, K=256)
    gemm_nn<64,64,16><<<dim3(NG4/64, DD/64), blk, 0, stream>>>(
        W_c, DD, W_w, NG4, nullptr, Fmat, NG4, DD, NG4, DD);
    // Bm = W_c[256:,:] @ W_w    (256 x 1024, K=256)
    gemm_nn<64,64,16><<<dim3(NG4/64, DD/64), blk, 0, stream>>>(
        W_c + (size_t)DD*DD, DD, W_w, NG4, nullptr, Bmw, NG4, DD, NG4, DD);
    // b2 = b_c @ W_w + b_w
    b2_kernel<<<dim3(NG4/256), blk, 0, stream>>>(b_c, W_w, b_w, B2);
    // fused persistent reader+writer (barrier-free, tagged-data sync)
    fused_kernel<<<dim3(BB*WGB), blk, FUSED_LDS, stream>>>(
        XW, Fmat, Bmw, B2, U_r, U_w, x, HRT, HWT, RHOT, CHUNK, PM, (float*)d_out);
}